// Round 1
// baseline (3055.894 us; speedup 1.0000x reference)
//
#include <hip/hip_runtime.h>

#define B_   4
#define T_   2048
#define BT_  8192
#define INL  15
#define DM   256
#define DI   512
#define DX   1024
#define DS_  16
#define DR_  16
#define NO_  48
#define NL   4

__device__ __forceinline__ float sigmoidf_(float x){ return 1.f/(1.f+__expf(-x)); }

// h[bt][m] = sum_k x[bt][k] * in_W[m][k]   (K=15)
__global__ void k_ingemm(const float* __restrict__ x, const float* __restrict__ W,
                         float* __restrict__ h){
    int g  = blockIdx.x*256 + threadIdx.x;   // g = bt*256 + m
    int bt = g >> 8, m = g & 255;
    const float* xr = x + bt*INL;
    const float* wr = W + m*INL;
    float acc = 0.f;
#pragma unroll
    for(int k=0;k<INL;k++) acc += xr[k]*wr[k];
    h[g] = acc;
}

// res = h (+ res_prev); hn = LN(res)*w+b. One wave per token (64 lanes x float4).
__global__ void k_resln(const float* __restrict__ h, float* __restrict__ res,
                        float* __restrict__ hn, const float* __restrict__ w,
                        const float* __restrict__ b, int addRes){
    int wv = threadIdx.x >> 6, lane = threadIdx.x & 63;
    int bt = blockIdx.x*4 + wv;
    float4 v = ((const float4*)(h + (size_t)bt*DM))[lane];
    if(addRes){
        float4 r = ((const float4*)(res + (size_t)bt*DM))[lane];
        v.x+=r.x; v.y+=r.y; v.z+=r.z; v.w+=r.w;
    }
    ((float4*)(res + (size_t)bt*DM))[lane] = v;
    float s  = v.x+v.y+v.z+v.w;
    float ss = v.x*v.x+v.y*v.y+v.z*v.z+v.w*v.w;
#pragma unroll
    for(int m=1;m<64;m<<=1){ s += __shfl_xor(s,m); ss += __shfl_xor(ss,m); }
    float mean = s*(1.f/DM);
    float var  = ss*(1.f/DM) - mean*mean;
    float inv  = rsqrtf(var + 1e-5f);
    float4 wt = ((const float4*)w)[lane];
    float4 bs = ((const float4*)b)[lane];
    float4 o;
    o.x = (v.x-mean)*inv*wt.x + bs.x;
    o.y = (v.y-mean)*inv*wt.y + bs.y;
    o.z = (v.z-mean)*inv*wt.z + bs.z;
    o.w = (v.w-mean)*inv*wt.w + bs.w;
    ((float4*)(hn + (size_t)bt*DM))[lane] = o;
}

// C[M][N] = A[M][K] @ Bw[N][K]^T   fp32 tiled, 64x64 tile, 256 threads, 4x4/thread
template<int BM,int BN,int BK>
__global__ void k_gemm(const float* __restrict__ A, const float* __restrict__ Bw,
                       float* __restrict__ C, int M, int N, int K){
    __shared__ float As[BK][BM+4];
    __shared__ float Bs[BK][BN+4];
    int tx = threadIdx.x & 15, ty = threadIdx.x >> 4;
    int n0 = blockIdx.x*BN, m0 = blockIdx.y*BM;
    int lrow = threadIdx.x >> 2;         // 0..63
    int lk   = (threadIdx.x & 3) * 4;    // 0,4,8,12
    float acc[4][4] = {};
    for(int k0=0;k0<K;k0+=BK){
        float4 av = *(const float4*)(A  + (size_t)(m0+lrow)*K + k0 + lk);
        float4 bv = *(const float4*)(Bw + (size_t)(n0+lrow)*K + k0 + lk);
        As[lk+0][lrow]=av.x; As[lk+1][lrow]=av.y; As[lk+2][lrow]=av.z; As[lk+3][lrow]=av.w;
        Bs[lk+0][lrow]=bv.x; Bs[lk+1][lrow]=bv.y; Bs[lk+2][lrow]=bv.z; Bs[lk+3][lrow]=bv.w;
        __syncthreads();
#pragma unroll
        for(int kk=0;kk<BK;kk++){
            float4 a = *(const float4*)(&As[kk][ty*4]);
            float4 b = *(const float4*)(&Bs[kk][tx*4]);
            acc[0][0]+=a.x*b.x; acc[0][1]+=a.x*b.y; acc[0][2]+=a.x*b.z; acc[0][3]+=a.x*b.w;
            acc[1][0]+=a.y*b.x; acc[1][1]+=a.y*b.y; acc[1][2]+=a.y*b.z; acc[1][3]+=a.y*b.w;
            acc[2][0]+=a.z*b.x; acc[2][1]+=a.z*b.y; acc[2][2]+=a.z*b.z; acc[2][3]+=a.z*b.w;
            acc[3][0]+=a.w*b.x; acc[3][1]+=a.w*b.y; acc[3][2]+=a.w*b.z; acc[3][3]+=a.w*b.w;
        }
        __syncthreads();
    }
#pragma unroll
    for(int i=0;i<4;i++){
        float4 o = make_float4(acc[i][0],acc[i][1],acc[i][2],acc[i][3]);
        *(float4*)(C + (size_t)(m0+ty*4+i)*N + n0 + tx*4) = o;
    }
}

// depthwise causal conv(4) + bias + SiLU on xz[:, :512] -> xh
__global__ void k_conv(const float* __restrict__ xz, const float* __restrict__ cw,
                       const float* __restrict__ cb, float* __restrict__ xh){
    int g  = blockIdx.x*256 + threadIdx.x;   // g = bt*512 + d
    int bt = g >> 9, d = g & 511;
    int t  = bt & (T_-1);
    const float* wr = cw + d*4;
    float acc = cb[d];
#pragma unroll
    for(int k=0;k<4;k++){
        int tt = t - 3 + k;
        if(tt >= 0) acc += xz[(size_t)(bt-3+k)*DX + d] * wr[k];
    }
    xh[g] = acc * sigmoidf_(acc);
}

// fused: dbl = xh @ xpW^T (48 outs); Bm,C -> bc[bt][32]; dt = softplus(dbl[:, :16] @ dtW^T + dtb)
__global__ void k_xproj(const float* __restrict__ xh, const float* __restrict__ xpW,
                        const float* __restrict__ dtW, const float* __restrict__ dtbias,
                        float* __restrict__ bc, float* __restrict__ dtO){
    __shared__ float xs[16*516];
    __shared__ float dls[16][16];
    int bt0 = blockIdx.x*16;
    // stage 16 tokens x 512
#pragma unroll
    for(int j=0;j<8;j++){
        int e = (threadIdx.x + j*256)*4;
        float4 v = *(const float4*)(xh + (size_t)bt0*DI + e);
        int row = e >> 9, col = e & 511;
        *(float4*)(&xs[row*516 + col]) = v;
    }
    __syncthreads();
    int tok = threadIdx.x & 15, os = threadIdx.x >> 4;
    const float* xr = &xs[tok*516];
    const float* w0 = xpW + (size_t)os*DI;
    const float* w1 = xpW + (size_t)(os+16)*DI;
    const float* w2 = xpW + (size_t)(os+32)*DI;
    float a0=0.f, a1=0.f, a2=0.f;
#pragma unroll 8
    for(int k=0;k<DI;k++){
        float xv = xr[k];
        a0 += xv*w0[k]; a1 += xv*w1[k]; a2 += xv*w2[k];
    }
    dls[tok][os] = a0;
    bc[(size_t)(bt0+tok)*32 + os]      = a1;
    bc[(size_t)(bt0+tok)*32 + 16 + os] = a2;
    __syncthreads();
    int tok2 = threadIdx.x >> 4, dsl = threadIdx.x & 15;
#pragma unroll
    for(int jj=0;jj<32;jj++){
        int d = jj*16 + dsl;
        const float* wr = dtW + d*DR_;
        float acc = dtbias[d];
#pragma unroll
        for(int r=0;r<16;r++) acc += dls[tok2][r]*wr[r];
        float sp = fmaxf(acc,0.f) + log1pf(__expf(-fabsf(acc)));
        dtO[(size_t)(bt0+tok2)*DI + d] = sp;
    }
}

// selective scan: one block handles (b, 16 d-channels), thread = (dd, nn); chunked LDS staging.
// outputs ys = (scan_y + Dp*xh) * silu(z)
__global__ void __launch_bounds__(256) k_scan(const float* __restrict__ dt,
    const float* __restrict__ xh, const float* __restrict__ xz,
    const float* __restrict__ bc, const float* __restrict__ A_log,
    const float* __restrict__ Dpar, float* __restrict__ ys){
    __shared__ float dts[64*16], xhs[64*16], zs[64*16], bms[64*16], cs[64*16], yss[64*16];
    int b = blockIdx.x >> 5, dblk = blockIdx.x & 31;
    int d0 = dblk*16;
    int dd = threadIdx.x >> 4, nn = threadIdx.x & 15;
    int d  = d0 + dd;
    float a  = -__expf(A_log[d*DS_ + nn]);
    float Dp = Dpar[d];
    float st = 0.f;
    int base = b*T_;
    for(int t0=0;t0<T_;t0+=64){
#pragma unroll
        for(int j=0;j<4;j++){
            int e = threadIdx.x + j*256;
            int tt = e >> 4, c = e & 15;
            size_t bt = (size_t)(base + t0 + tt);
            dts[e] = dt[bt*DI + d0 + c];
            xhs[e] = xh[bt*DI + d0 + c];
            zs[e]  = xz[bt*DX + DI + d0 + c];
        }
#pragma unroll
        for(int j=0;j<8;j++){
            int e = threadIdx.x + j*256;
            int tt = e >> 5, c = e & 31;
            float v = bc[(size_t)(base + t0 + tt)*32 + c];
            if(c < 16) bms[tt*16 + c] = v; else cs[tt*16 + (c-16)] = v;
        }
        __syncthreads();
        for(int tt=0;tt<64;tt++){
            float dtv = dts[tt*16+dd];
            float xhv = xhs[tt*16+dd];
            float dA  = __expf(dtv*a);
            st = dA*st + dtv*bms[tt*16+nn]*xhv;
            float ctr = st*cs[tt*16+nn];
            ctr += __shfl_xor(ctr,1);
            ctr += __shfl_xor(ctr,2);
            ctr += __shfl_xor(ctr,4);
            ctr += __shfl_xor(ctr,8);
            if(nn==0){
                float zv = zs[tt*16+dd];
                float y  = ctr + Dp*xhv;
                yss[tt*16+dd] = y * zv * sigmoidf_(zv);
            }
        }
        __syncthreads();
#pragma unroll
        for(int j=0;j<4;j++){
            int e = threadIdx.x + j*256;
            int tt = e >> 4, c = e & 15;
            ys[(size_t)(base + t0 + tt)*DI + d0 + c] = yss[e];
        }
        __syncthreads();
    }
}

// out[bt] = dot(h[bt, :256], out_W)
__global__ void k_outw(const float* __restrict__ h, const float* __restrict__ ow,
                       float* __restrict__ out){
    int wv = threadIdx.x >> 6, lane = threadIdx.x & 63;
    int bt = blockIdx.x*4 + wv;
    float4 v = ((const float4*)(h + (size_t)bt*DM))[lane];
    float4 w = ((const float4*)ow)[lane];
    float s = v.x*w.x + v.y*w.y + v.z*w.z + v.w*w.w;
#pragma unroll
    for(int m=1;m<64;m<<=1) s += __shfl_xor(s,m);
    if(lane==0) out[bt] = s;
}

extern "C" void kernel_launch(void* const* d_in, const int* in_sizes, int n_in,
                              void* d_out, int out_size, void* d_ws, size_t ws_size,
                              hipStream_t stream){
    const float* x_src    = (const float*)d_in[0];
    // d_in[1] = single_eval_pos (unused by reference)
    const float* in_W     = (const float*)d_in[2];
    const float* norm_w   = (const float*)d_in[3];
    const float* norm_b   = (const float*)d_in[4];
    const float* inproj_W = (const float*)d_in[5];
    const float* conv_w   = (const float*)d_in[6];
    const float* conv_b   = (const float*)d_in[7];
    const float* xproj_W  = (const float*)d_in[8];
    const float* dtproj_W = (const float*)d_in[9];
    const float* dtproj_b = (const float*)d_in[10];
    const float* A_log    = (const float*)d_in[11];
    const float* D_param  = (const float*)d_in[12];
    const float* outproj_W= (const float*)d_in[13];
    const float* out_W    = (const float*)d_in[14];

    float* ws  = (float*)d_ws;
    float* h   = ws;                 // BT*DM
    float* res = h   + (size_t)BT_*DM;
    float* hn  = res + (size_t)BT_*DM;
    float* xz  = hn  + (size_t)BT_*DM;   // BT*DX
    float* xh  = xz  + (size_t)BT_*DX;   // BT*DI
    float* bcb = xh  + (size_t)BT_*DI;   // BT*32
    float* dtb = bcb + (size_t)BT_*32;   // BT*DI
    float* ysb = dtb + (size_t)BT_*DI;   // BT*DI

    k_ingemm<<<BT_*DM/256, 256, 0, stream>>>(x_src, in_W, h);
    for(int i=0;i<NL;i++){
        k_resln<<<BT_/4, 256, 0, stream>>>(h, res, hn, norm_w + i*DM, norm_b + i*DM, i>0 ? 1 : 0);
        k_gemm<64,64,16><<<dim3(DX/64, BT_/64), 256, 0, stream>>>(hn, inproj_W + (size_t)i*DX*DM, xz, BT_, DX, DM);
        k_conv<<<BT_*DI/256, 256, 0, stream>>>(xz, conv_w + i*DI*4, conv_b + i*DI, xh);
        k_xproj<<<BT_/16, 256, 0, stream>>>(xh, xproj_W + (size_t)i*NO_*DI,
                                            dtproj_W + (size_t)i*DI*DR_, dtproj_b + i*DI, bcb, dtb);
        k_scan<<<B_*(DI/16), 256, 0, stream>>>(dtb, xh, xz, bcb,
                                               A_log + (size_t)i*DI*DS_, D_param + i*DI, ysb);
        k_gemm<64,64,16><<<dim3(DM/64, BT_/64), 256, 0, stream>>>(ysb, outproj_W + (size_t)i*DM*DI, h, BT_, DM, DI);
    }
    k_outw<<<BT_/4, 256, 0, stream>>>(h, out_W, (float*)d_out);
}

// Round 2
// 1003.943 us; speedup vs baseline: 3.0439x; 3.0439x over previous
//
#include <hip/hip_runtime.h>

#define B_   4
#define T_   2048
#define BT_  8192
#define INL  15
#define DM   256
#define DI   512
#define DX   1024
#define DS_  16
#define DR_  16
#define NO_  48
#define NL   4
#define NC_  64
#define LCH  32

__device__ __forceinline__ float sigmoidf_(float x){ return 1.f/(1.f+__expf(-x)); }

__device__ __forceinline__ void ld16(const float* __restrict__ p, float* v){
    const float4* q = (const float4*)p;
    float4 x0=q[0],x1=q[1],x2=q[2],x3=q[3];
    v[0]=x0.x; v[1]=x0.y; v[2]=x0.z; v[3]=x0.w;
    v[4]=x1.x; v[5]=x1.y; v[6]=x1.z; v[7]=x1.w;
    v[8]=x2.x; v[9]=x2.y; v[10]=x2.z; v[11]=x2.w;
    v[12]=x3.x; v[13]=x3.y; v[14]=x3.z; v[15]=x3.w;
}
__device__ __forceinline__ void st16(float* __restrict__ p, const float* v){
    float4* q = (float4*)p;
    q[0] = make_float4(v[0],v[1],v[2],v[3]);
    q[1] = make_float4(v[4],v[5],v[6],v[7]);
    q[2] = make_float4(v[8],v[9],v[10],v[11]);
    q[3] = make_float4(v[12],v[13],v[14],v[15]);
}

// h[bt][m] = sum_k x[bt][k] * in_W[m][k]   (K=15)
__global__ void k_ingemm(const float* __restrict__ x, const float* __restrict__ W,
                         float* __restrict__ h){
    int g  = blockIdx.x*256 + threadIdx.x;
    int bt = g >> 8, m = g & 255;
    const float* xr = x + bt*INL;
    const float* wr = W + m*INL;
    float acc = 0.f;
#pragma unroll
    for(int k=0;k<INL;k++) acc += xr[k]*wr[k];
    h[g] = acc;
}

// res = h (+ res_prev); hn = LN(res)*w+b. One wave per token.
__global__ void k_resln(const float* __restrict__ h, float* __restrict__ res,
                        float* __restrict__ hn, const float* __restrict__ w,
                        const float* __restrict__ b, int addRes){
    int wv = threadIdx.x >> 6, lane = threadIdx.x & 63;
    int bt = blockIdx.x*4 + wv;
    float4 v = ((const float4*)(h + (size_t)bt*DM))[lane];
    if(addRes){
        float4 r = ((const float4*)(res + (size_t)bt*DM))[lane];
        v.x+=r.x; v.y+=r.y; v.z+=r.z; v.w+=r.w;
    }
    ((float4*)(res + (size_t)bt*DM))[lane] = v;
    float s  = v.x+v.y+v.z+v.w;
    float ss = v.x*v.x+v.y*v.y+v.z*v.z+v.w*v.w;
#pragma unroll
    for(int m=1;m<64;m<<=1){ s += __shfl_xor(s,m); ss += __shfl_xor(ss,m); }
    float mean = s*(1.f/DM);
    float var  = ss*(1.f/DM) - mean*mean;
    float inv  = rsqrtf(var + 1e-5f);
    float4 wt = ((const float4*)w)[lane];
    float4 bs = ((const float4*)b)[lane];
    float4 o;
    o.x = (v.x-mean)*inv*wt.x + bs.x;
    o.y = (v.y-mean)*inv*wt.y + bs.y;
    o.z = (v.z-mean)*inv*wt.z + bs.z;
    o.w = (v.w-mean)*inv*wt.w + bs.w;
    ((float4*)(hn + (size_t)bt*DM))[lane] = o;
}

// C[M][N] = A[M][K] @ Bw[N][K]^T
template<int BM,int BN,int BK>
__global__ void k_gemm(const float* __restrict__ A, const float* __restrict__ Bw,
                       float* __restrict__ C, int M, int N, int K){
    __shared__ float As[BK][BM+4];
    __shared__ float Bs[BK][BN+4];
    int tx = threadIdx.x & 15, ty = threadIdx.x >> 4;
    int n0 = blockIdx.x*BN, m0 = blockIdx.y*BM;
    int lrow = threadIdx.x >> 2;
    int lk   = (threadIdx.x & 3) * 4;
    float acc[4][4] = {};
    for(int k0=0;k0<K;k0+=BK){
        float4 av = *(const float4*)(A  + (size_t)(m0+lrow)*K + k0 + lk);
        float4 bv = *(const float4*)(Bw + (size_t)(n0+lrow)*K + k0 + lk);
        As[lk+0][lrow]=av.x; As[lk+1][lrow]=av.y; As[lk+2][lrow]=av.z; As[lk+3][lrow]=av.w;
        Bs[lk+0][lrow]=bv.x; Bs[lk+1][lrow]=bv.y; Bs[lk+2][lrow]=bv.z; Bs[lk+3][lrow]=bv.w;
        __syncthreads();
#pragma unroll
        for(int kk=0;kk<BK;kk++){
            float4 a = *(const float4*)(&As[kk][ty*4]);
            float4 b = *(const float4*)(&Bs[kk][tx*4]);
            acc[0][0]+=a.x*b.x; acc[0][1]+=a.x*b.y; acc[0][2]+=a.x*b.z; acc[0][3]+=a.x*b.w;
            acc[1][0]+=a.y*b.x; acc[1][1]+=a.y*b.y; acc[1][2]+=a.y*b.z; acc[1][3]+=a.y*b.w;
            acc[2][0]+=a.z*b.x; acc[2][1]+=a.z*b.y; acc[2][2]+=a.z*b.z; acc[2][3]+=a.z*b.w;
            acc[3][0]+=a.w*b.x; acc[3][1]+=a.w*b.y; acc[3][2]+=a.w*b.z; acc[3][3]+=a.w*b.w;
        }
        __syncthreads();
    }
#pragma unroll
    for(int i=0;i<4;i++){
        float4 o = make_float4(acc[i][0],acc[i][1],acc[i][2],acc[i][3]);
        *(float4*)(C + (size_t)(m0+ty*4+i)*N + n0 + tx*4) = o;
    }
}

// depthwise causal conv(4) + bias + SiLU
__global__ void k_conv(const float* __restrict__ xz, const float* __restrict__ cw,
                       const float* __restrict__ cb, float* __restrict__ xh){
    int g  = blockIdx.x*256 + threadIdx.x;
    int bt = g >> 9, d = g & 511;
    int t  = bt & (T_-1);
    const float* wr = cw + d*4;
    float acc = cb[d];
#pragma unroll
    for(int k=0;k<4;k++){
        int tt = t - 3 + k;
        if(tt >= 0) acc += xz[(size_t)(bt-3+k)*DX + d] * wr[k];
    }
    xh[g] = acc * sigmoidf_(acc);
}

// fused xproj + dtproj + softplus
__global__ void k_xproj(const float* __restrict__ xh, const float* __restrict__ xpW,
                        const float* __restrict__ dtW, const float* __restrict__ dtbias,
                        float* __restrict__ bc, float* __restrict__ dtO){
    __shared__ float xs[16*516];
    __shared__ float dls[16][16];
    int bt0 = blockIdx.x*16;
#pragma unroll
    for(int j=0;j<8;j++){
        int e = (threadIdx.x + j*256)*4;
        float4 v = *(const float4*)(xh + (size_t)bt0*DI + e);
        int row = e >> 9, col = e & 511;
        *(float4*)(&xs[row*516 + col]) = v;
    }
    __syncthreads();
    int tok = threadIdx.x & 15, os = threadIdx.x >> 4;
    const float* xr = &xs[tok*516];
    const float* w0 = xpW + (size_t)os*DI;
    const float* w1 = xpW + (size_t)(os+16)*DI;
    const float* w2 = xpW + (size_t)(os+32)*DI;
    float a0=0.f, a1=0.f, a2=0.f;
#pragma unroll 8
    for(int k=0;k<DI;k++){
        float xv = xr[k];
        a0 += xv*w0[k]; a1 += xv*w1[k]; a2 += xv*w2[k];
    }
    dls[tok][os] = a0;
    bc[(size_t)(bt0+tok)*32 + os]      = a1;
    bc[(size_t)(bt0+tok)*32 + 16 + os] = a2;
    __syncthreads();
    int tok2 = threadIdx.x >> 4, dsl = threadIdx.x & 15;
#pragma unroll
    for(int jj=0;jj<32;jj++){
        int d = jj*16 + dsl;
        const float* wr = dtW + d*DR_;
        float acc = dtbias[d];
#pragma unroll
        for(int r=0;r<16;r++) acc += dls[tok2][r]*wr[r];
        float sp = fmaxf(acc,0.f) + log1pf(__expf(-fabsf(acc)));
        dtO[(size_t)(bt0+tok2)*DI + d] = sp;
    }
}

// ---- chunk-parallel scan: pass 1 (per-chunk local scan, zero init) ----
// thread = one d-channel, st[16] in regs. Records S (final local state) and sum(dt).
__global__ void __launch_bounds__(256) k_scan1(const float* __restrict__ dt,
    const float* __restrict__ xh, const float* __restrict__ bc,
    const float* __restrict__ A_log, float* __restrict__ S, float* __restrict__ sdt){
    int d = blockIdx.x*256 + threadIdx.x;
    int c = blockIdx.y, b = blockIdx.z;
    float a[16]; ld16(A_log + (size_t)d*16, a);
#pragma unroll
    for(int n=0;n<16;n++) a[n] = -__expf(a[n]);
    float st[16];
#pragma unroll
    for(int n=0;n<16;n++) st[n] = 0.f;
    float sd = 0.f;
    int base = b*T_ + c*LCH;
#pragma unroll 2
    for(int t=0;t<LCH;t++){
        int bt = base + t;
        float dtv = dt[(size_t)bt*DI + d];
        float xhv = xh[(size_t)bt*DI + d];
        float bv[16]; ld16(bc + (size_t)bt*32, bv);
        float dx = dtv*xhv;
        sd += dtv;
#pragma unroll
        for(int n=0;n<16;n++) st[n] = __expf(dtv*a[n])*st[n] + dx*bv[n];
    }
    st16(S + (((size_t)b*NC_ + c)*DI + d)*16, st);
    sdt[((size_t)b*NC_ + c)*DI + d] = sd;
}

// ---- pass 2: scan over chunks; H_c = P_{c-1} H_{c-1} + S_{c-1}, P = exp(a*sum_dt) ----
__global__ void k_scan2(const float* __restrict__ S, const float* __restrict__ sdt,
                        const float* __restrict__ A_log, float* __restrict__ Hinit){
    int g = blockIdx.x*256 + threadIdx.x;   // g = b*8192 + d*16 + n
    int b = g >> 13;
    int dn = g & 8191;
    int d = dn >> 4;
    float a = -__expf(A_log[dn]);
    float H = 0.f;
    for(int c=0;c<NC_;c++){
        size_t o = ((size_t)(b*NC_ + c))*8192 + dn;
        Hinit[o] = H;
        float sd = sdt[(size_t)(b*NC_ + c)*DI + d];
        H = __expf(sd*a)*H + S[o];
    }
}

// ---- pass 3: replay chunk from Hinit, emit gated output ----
__global__ void __launch_bounds__(256) k_scan3(const float* __restrict__ dt,
    const float* __restrict__ xh, const float* __restrict__ xz,
    const float* __restrict__ bc, const float* __restrict__ A_log,
    const float* __restrict__ Dpar, const float* __restrict__ Hinit,
    float* __restrict__ ys){
    int d = blockIdx.x*256 + threadIdx.x;
    int c = blockIdx.y, b = blockIdx.z;
    float a[16]; ld16(A_log + (size_t)d*16, a);
#pragma unroll
    for(int n=0;n<16;n++) a[n] = -__expf(a[n]);
    float st[16]; ld16(Hinit + (((size_t)b*NC_ + c)*DI + d)*16, st);
    float Dp = Dpar[d];
    int base = b*T_ + c*LCH;
#pragma unroll 2
    for(int t=0;t<LCH;t++){
        int bt = base + t;
        float dtv = dt[(size_t)bt*DI + d];
        float xhv = xh[(size_t)bt*DI + d];
        float bv[16]; ld16(bc + (size_t)bt*32, bv);
        float cv[16]; ld16(bc + (size_t)bt*32 + 16, cv);
        float dx = dtv*xhv;
        float y = 0.f;
#pragma unroll
        for(int n=0;n<16;n++){
            st[n] = __expf(dtv*a[n])*st[n] + dx*bv[n];
            y += st[n]*cv[n];
        }
        float zv = xz[(size_t)bt*DX + DI + d];
        y += Dp*xhv;
        ys[(size_t)bt*DI + d] = y * zv * sigmoidf_(zv);
    }
}

// out[bt] = dot(h[bt, :256], out_W)
__global__ void k_outw(const float* __restrict__ h, const float* __restrict__ ow,
                       float* __restrict__ out){
    int wv = threadIdx.x >> 6, lane = threadIdx.x & 63;
    int bt = blockIdx.x*4 + wv;
    float4 v = ((const float4*)(h + (size_t)bt*DM))[lane];
    float4 w = ((const float4*)ow)[lane];
    float s = v.x*w.x + v.y*w.y + v.z*w.z + v.w*w.w;
#pragma unroll
    for(int m=1;m<64;m<<=1) s += __shfl_xor(s,m);
    if(lane==0) out[bt] = s;
}

extern "C" void kernel_launch(void* const* d_in, const int* in_sizes, int n_in,
                              void* d_out, int out_size, void* d_ws, size_t ws_size,
                              hipStream_t stream){
    const float* x_src    = (const float*)d_in[0];
    const float* in_W     = (const float*)d_in[2];
    const float* norm_w   = (const float*)d_in[3];
    const float* norm_b   = (const float*)d_in[4];
    const float* inproj_W = (const float*)d_in[5];
    const float* conv_w   = (const float*)d_in[6];
    const float* conv_b   = (const float*)d_in[7];
    const float* xproj_W  = (const float*)d_in[8];
    const float* dtproj_W = (const float*)d_in[9];
    const float* dtproj_b = (const float*)d_in[10];
    const float* A_log    = (const float*)d_in[11];
    const float* D_param  = (const float*)d_in[12];
    const float* outproj_W= (const float*)d_in[13];
    const float* out_W    = (const float*)d_in[14];

    float* ws  = (float*)d_ws;
    float* h   = ws;                       // BT*DM  (aliased as S during scan: both 2.097M floats)
    float* res = h   + (size_t)BT_*DM;
    float* hn  = res + (size_t)BT_*DM;     // aliased as Hinit during scan
    float* xz  = hn  + (size_t)BT_*DM;     // BT*DX
    float* xh  = xz  + (size_t)BT_*DX;     // BT*DI
    float* bcb = xh  + (size_t)BT_*DI;     // BT*32
    float* dtb = bcb + (size_t)BT_*32;     // BT*DI
    float* ysb = dtb + (size_t)BT_*DI;     // BT*DI
    float* sdtb= ysb + (size_t)BT_*DI;     // B*NC*DI = 131072
    float* Sbuf = h;    // dead during scan (consumed by k_resln, rewritten by outproj)
    float* Hbuf = hn;   // dead during scan (consumed by inproj gemm)

    k_ingemm<<<BT_*DM/256, 256, 0, stream>>>(x_src, in_W, h);
    for(int i=0;i<NL;i++){
        k_resln<<<BT_/4, 256, 0, stream>>>(h, res, hn, norm_w + i*DM, norm_b + i*DM, i>0 ? 1 : 0);
        k_gemm<64,64,16><<<dim3(DX/64, BT_/64), 256, 0, stream>>>(hn, inproj_W + (size_t)i*DX*DM, xz, BT_, DX, DM);
        k_conv<<<BT_*DI/256, 256, 0, stream>>>(xz, conv_w + i*DI*4, conv_b + i*DI, xh);
        k_xproj<<<BT_/16, 256, 0, stream>>>(xh, xproj_W + (size_t)i*NO_*DI,
                                            dtproj_W + (size_t)i*DI*DR_, dtproj_b + i*DI, bcb, dtb);
        k_scan1<<<dim3(DI/256, NC_, B_), 256, 0, stream>>>(dtb, xh, bcb, A_log + (size_t)i*DI*DS_, Sbuf, sdtb);
        k_scan2<<<B_*DI*DS_/256, 256, 0, stream>>>(Sbuf, sdtb, A_log + (size_t)i*DI*DS_, Hbuf);
        k_scan3<<<dim3(DI/256, NC_, B_), 256, 0, stream>>>(dtb, xh, xz, bcb, A_log + (size_t)i*DI*DS_,
                                                           D_param + i*DI, Hbuf, ysb);
        k_gemm<64,64,16><<<dim3(DM/64, BT_/64), 256, 0, stream>>>(ysb, outproj_W + (size_t)i*DM*DI, h, BT_, DM, DI);
    }
    k_outw<<<BT_/4, 256, 0, stream>>>(h, out_W, (float*)d_out);
}

// Round 3
// 802.356 us; speedup vs baseline: 3.8086x; 1.2512x over previous
//
#include <hip/hip_runtime.h>

#define B_   4
#define T_   2048
#define BT_  8192
#define INL  15
#define DM   256
#define DI   512
#define DX   1024
#define DS_  16
#define DR_  16
#define NO_  48
#define NL   4
#define NC_  64
#define LCH  32

typedef short bf16x8 __attribute__((ext_vector_type(8)));
typedef float f32x4  __attribute__((ext_vector_type(4)));

__device__ __forceinline__ float sigmoidf_(float x){ return 1.f/(1.f+__expf(-x)); }

__device__ __forceinline__ unsigned short f2bf(float x){
    union { float f; unsigned u; } v; v.f = x;
    unsigned r = (v.u + 0x7FFFu + ((v.u >> 16) & 1u)) >> 16;
    return (unsigned short)r;
}
__device__ __forceinline__ float bf2f(unsigned short h){
    union { unsigned u; float f; } v; v.u = ((unsigned)h) << 16;
    return v.f;
}

__device__ __forceinline__ void ld16(const float* __restrict__ p, float* v){
    const float4* q = (const float4*)p;
    float4 x0=q[0],x1=q[1],x2=q[2],x3=q[3];
    v[0]=x0.x; v[1]=x0.y; v[2]=x0.z; v[3]=x0.w;
    v[4]=x1.x; v[5]=x1.y; v[6]=x1.z; v[7]=x1.w;
    v[8]=x2.x; v[9]=x2.y; v[10]=x2.z; v[11]=x2.w;
    v[12]=x3.x; v[13]=x3.y; v[14]=x3.z; v[15]=x3.w;
}
__device__ __forceinline__ void st16(float* __restrict__ p, const float* v){
    float4* q = (float4*)p;
    q[0] = make_float4(v[0],v[1],v[2],v[3]);
    q[1] = make_float4(v[4],v[5],v[6],v[7]);
    q[2] = make_float4(v[8],v[9],v[10],v[11]);
    q[3] = make_float4(v[12],v[13],v[14],v[15]);
}

// convert fp32 array -> bf16 hi/lo split (4 elems/thread)
__global__ void k_cvtW(const float* __restrict__ W, unsigned short* __restrict__ hi,
                       unsigned short* __restrict__ lo, int n4){
    int g = blockIdx.x*256 + threadIdx.x;
    if(g >= n4) return;
    float4 v = ((const float4*)W)[g];
    ushort4 h, l;
    h.x = f2bf(v.x); l.x = f2bf(v.x - bf2f(h.x));
    h.y = f2bf(v.y); l.y = f2bf(v.y - bf2f(h.y));
    h.z = f2bf(v.z); l.z = f2bf(v.z - bf2f(h.z));
    h.w = f2bf(v.w); l.w = f2bf(v.w - bf2f(h.w));
    ((ushort4*)hi)[g] = h;
    ((ushort4*)lo)[g] = l;
}

// h[bt][m] = sum_k x[bt][k] * in_W[m][k]   (K=15)
__global__ void k_ingemm(const float* __restrict__ x, const float* __restrict__ W,
                         float* __restrict__ h){
    int g  = blockIdx.x*256 + threadIdx.x;
    int bt = g >> 8, m = g & 255;
    const float* xr = x + bt*INL;
    const float* wr = W + m*INL;
    float acc = 0.f;
#pragma unroll
    for(int k=0;k<INL;k++) acc += xr[k]*wr[k];
    h[g] = acc;
}

// res = h (+ res_prev); hn = LN(res)*w+b -> bf16 hi/lo. One wave per token.
__global__ void k_resln(const float* __restrict__ h, float* __restrict__ res,
                        unsigned short* __restrict__ hnhi, unsigned short* __restrict__ hnlo,
                        const float* __restrict__ w, const float* __restrict__ b, int addRes){
    int wv = threadIdx.x >> 6, lane = threadIdx.x & 63;
    int bt = blockIdx.x*4 + wv;
    float4 v = ((const float4*)(h + (size_t)bt*DM))[lane];
    if(addRes){
        float4 r = ((const float4*)(res + (size_t)bt*DM))[lane];
        v.x+=r.x; v.y+=r.y; v.z+=r.z; v.w+=r.w;
    }
    ((float4*)(res + (size_t)bt*DM))[lane] = v;
    float s  = v.x+v.y+v.z+v.w;
    float ss = v.x*v.x+v.y*v.y+v.z*v.z+v.w*v.w;
#pragma unroll
    for(int m=1;m<64;m<<=1){ s += __shfl_xor(s,m); ss += __shfl_xor(ss,m); }
    float mean = s*(1.f/DM);
    float var  = ss*(1.f/DM) - mean*mean;
    float inv  = rsqrtf(var + 1e-5f);
    float4 wt = ((const float4*)w)[lane];
    float4 bs = ((const float4*)b)[lane];
    float4 o;
    o.x = (v.x-mean)*inv*wt.x + bs.x;
    o.y = (v.y-mean)*inv*wt.y + bs.y;
    o.z = (v.z-mean)*inv*wt.z + bs.z;
    o.w = (v.w-mean)*inv*wt.w + bs.w;
    ushort4 hh, ll;
    hh.x = f2bf(o.x); ll.x = f2bf(o.x - bf2f(hh.x));
    hh.y = f2bf(o.y); ll.y = f2bf(o.y - bf2f(hh.y));
    hh.z = f2bf(o.z); ll.z = f2bf(o.z - bf2f(hh.z));
    hh.w = f2bf(o.w); ll.w = f2bf(o.w - bf2f(hh.w));
    ((ushort4*)(hnhi + (size_t)bt*DM))[lane] = hh;
    ((ushort4*)(hnlo + (size_t)bt*DM))[lane] = ll;
}

// C[M][N] = A[M][K] @ Bw[N][K]^T via bf16 MFMA with hi/lo split (3 products).
// 256 threads = 4 waves in 2x2; wave tile (BM/2)x(BN/2); 16x16x32 MFMA fragments.
template<int BM,int BN>
__global__ void __launch_bounds__(256) k_gemm_bf3(
    const unsigned short* __restrict__ Ahi, const unsigned short* __restrict__ Alo,
    const unsigned short* __restrict__ Bhi, const unsigned short* __restrict__ Blo,
    float* __restrict__ C, int M, int N, int K)
{
    constexpr int LDP = 40;                 // padded LDS row pitch in shorts (80 B)
    constexpr int WM = BM/2, WN = BN/2;
    constexpr int MI_ = WM/16, NI_ = WN/16;
    __shared__ unsigned short sAh[BM*LDP], sAl[BM*LDP], sBh[BN*LDP], sBl[BN*LDP];
    int tid  = threadIdx.x;
    int wave = tid >> 6, lane = tid & 63;
    int wm0  = (wave >> 1) * WM, wn0 = (wave & 1) * WN;
    int m0   = blockIdx.y * BM, n0 = blockIdx.x * BN;
    int lr   = lane & 15;
    int kq   = (lane >> 4) * 8;
    int quad4 = (lane >> 4) * 4;

    f32x4 acc[MI_][NI_];
#pragma unroll
    for(int i=0;i<MI_;i++)
#pragma unroll
        for(int j=0;j<NI_;j++) acc[i][j] = (f32x4){0.f,0.f,0.f,0.f};

    for(int k0=0;k0<K;k0+=32){
#pragma unroll
        for(int i=tid;i<BM*4;i+=256){
            int r = i>>2, cg = (i&3)*8;
            size_t go = (size_t)(m0+r)*K + k0 + cg;
            *(float4*)(&sAh[r*LDP + cg]) = *(const float4*)(Ahi + go);
            *(float4*)(&sAl[r*LDP + cg]) = *(const float4*)(Alo + go);
        }
#pragma unroll
        for(int i=tid;i<BN*4;i+=256){
            int r = i>>2, cg = (i&3)*8;
            size_t go = (size_t)(n0+r)*K + k0 + cg;
            *(float4*)(&sBh[r*LDP + cg]) = *(const float4*)(Bhi + go);
            *(float4*)(&sBl[r*LDP + cg]) = *(const float4*)(Blo + go);
        }
        __syncthreads();
        bf16x8 ah[MI_], al[MI_], bh[NI_], bl[NI_];
#pragma unroll
        for(int mi=0;mi<MI_;mi++){
            int ro = (wm0 + mi*16 + lr)*LDP + kq;
            ah[mi] = *(const bf16x8*)(&sAh[ro]);
            al[mi] = *(const bf16x8*)(&sAl[ro]);
        }
#pragma unroll
        for(int ni=0;ni<NI_;ni++){
            int ro = (wn0 + ni*16 + lr)*LDP + kq;
            bh[ni] = *(const bf16x8*)(&sBh[ro]);
            bl[ni] = *(const bf16x8*)(&sBl[ro]);
        }
#pragma unroll
        for(int mi=0;mi<MI_;mi++)
#pragma unroll
            for(int ni=0;ni<NI_;ni++){
                acc[mi][ni] = __builtin_amdgcn_mfma_f32_16x16x32_bf16(ah[mi], bh[ni], acc[mi][ni], 0,0,0);
                acc[mi][ni] = __builtin_amdgcn_mfma_f32_16x16x32_bf16(ah[mi], bl[ni], acc[mi][ni], 0,0,0);
                acc[mi][ni] = __builtin_amdgcn_mfma_f32_16x16x32_bf16(al[mi], bh[ni], acc[mi][ni], 0,0,0);
            }
        __syncthreads();
    }
#pragma unroll
    for(int mi=0;mi<MI_;mi++)
#pragma unroll
        for(int ni=0;ni<NI_;ni++){
            int col = n0 + wn0 + ni*16 + lr;
#pragma unroll
            for(int r=0;r<4;r++){
                int row = m0 + wm0 + mi*16 + quad4 + r;
                C[(size_t)row*N + col] = acc[mi][ni][r];
            }
        }
}

// depthwise causal conv(4) + bias + SiLU
__global__ void k_conv(const float* __restrict__ xz, const float* __restrict__ cw,
                       const float* __restrict__ cb, float* __restrict__ xh){
    int g  = blockIdx.x*256 + threadIdx.x;
    int bt = g >> 9, d = g & 511;
    int t  = bt & (T_-1);
    const float* wr = cw + d*4;
    float acc = cb[d];
#pragma unroll
    for(int k=0;k<4;k++){
        int tt = t - 3 + k;
        if(tt >= 0) acc += xz[(size_t)(bt-3+k)*DX + d] * wr[k];
    }
    xh[g] = acc * sigmoidf_(acc);
}

// fused xproj + dtproj + softplus
__global__ void k_xproj(const float* __restrict__ xh, const float* __restrict__ xpW,
                        const float* __restrict__ dtW, const float* __restrict__ dtbias,
                        float* __restrict__ bc, float* __restrict__ dtO){
    __shared__ float xs[16*516];
    __shared__ float dls[16][16];
    int bt0 = blockIdx.x*16;
#pragma unroll
    for(int j=0;j<8;j++){
        int e = (threadIdx.x + j*256)*4;
        float4 v = *(const float4*)(xh + (size_t)bt0*DI + e);
        int row = e >> 9, col = e & 511;
        *(float4*)(&xs[row*516 + col]) = v;
    }
    __syncthreads();
    int tok = threadIdx.x & 15, os = threadIdx.x >> 4;
    const float* xr = &xs[tok*516];
    const float* w0 = xpW + (size_t)os*DI;
    const float* w1 = xpW + (size_t)(os+16)*DI;
    const float* w2 = xpW + (size_t)(os+32)*DI;
    float a0=0.f, a1=0.f, a2=0.f;
#pragma unroll 8
    for(int k=0;k<DI;k++){
        float xv = xr[k];
        a0 += xv*w0[k]; a1 += xv*w1[k]; a2 += xv*w2[k];
    }
    dls[tok][os] = a0;
    bc[(size_t)(bt0+tok)*32 + os]      = a1;
    bc[(size_t)(bt0+tok)*32 + 16 + os] = a2;
    __syncthreads();
    int tok2 = threadIdx.x >> 4, dsl = threadIdx.x & 15;
#pragma unroll
    for(int jj=0;jj<32;jj++){
        int d = jj*16 + dsl;
        const float* wr = dtW + d*DR_;
        float acc = dtbias[d];
#pragma unroll
        for(int r=0;r<16;r++) acc += dls[tok2][r]*wr[r];
        float sp = fmaxf(acc,0.f) + log1pf(__expf(-fabsf(acc)));
        dtO[(size_t)(bt0+tok2)*DI + d] = sp;
    }
}

// ---- chunk-parallel scan pass 1 ----
__global__ void __launch_bounds__(256) k_scan1(const float* __restrict__ dt,
    const float* __restrict__ xh, const float* __restrict__ bc,
    const float* __restrict__ A_log, float* __restrict__ S, float* __restrict__ sdt){
    int d = blockIdx.x*256 + threadIdx.x;
    int c = blockIdx.y, b = blockIdx.z;
    float a[16]; ld16(A_log + (size_t)d*16, a);
#pragma unroll
    for(int n=0;n<16;n++) a[n] = -__expf(a[n]);
    float st[16];
#pragma unroll
    for(int n=0;n<16;n++) st[n] = 0.f;
    float sd = 0.f;
    int base = b*T_ + c*LCH;
#pragma unroll 2
    for(int t=0;t<LCH;t++){
        int bt = base + t;
        float dtv = dt[(size_t)bt*DI + d];
        float xhv = xh[(size_t)bt*DI + d];
        float bv[16]; ld16(bc + (size_t)bt*32, bv);
        float dx = dtv*xhv;
        sd += dtv;
#pragma unroll
        for(int n=0;n<16;n++) st[n] = __expf(dtv*a[n])*st[n] + dx*bv[n];
    }
    st16(S + (((size_t)b*NC_ + c)*DI + d)*16, st);
    sdt[((size_t)b*NC_ + c)*DI + d] = sd;
}

// ---- pass 2: inter-chunk scan ----
__global__ void k_scan2(const float* __restrict__ S, const float* __restrict__ sdt,
                        const float* __restrict__ A_log, float* __restrict__ Hinit){
    int g = blockIdx.x*256 + threadIdx.x;
    int b = g >> 13;
    int dn = g & 8191;
    int d = dn >> 4;
    float a = -__expf(A_log[dn]);
    float H = 0.f;
    for(int c=0;c<NC_;c++){
        size_t o = ((size_t)(b*NC_ + c))*8192 + dn;
        Hinit[o] = H;
        float sd = sdt[(size_t)(b*NC_ + c)*DI + d];
        H = __expf(sd*a)*H + S[o];
    }
}

// ---- pass 3: replay + gate; writes ys as bf16 hi/lo ----
__global__ void __launch_bounds__(256) k_scan3(const float* __restrict__ dt,
    const float* __restrict__ xh, const float* __restrict__ xz,
    const float* __restrict__ bc, const float* __restrict__ A_log,
    const float* __restrict__ Dpar, const float* __restrict__ Hinit,
    unsigned short* __restrict__ yhi, unsigned short* __restrict__ ylo){
    int d = blockIdx.x*256 + threadIdx.x;
    int c = blockIdx.y, b = blockIdx.z;
    float a[16]; ld16(A_log + (size_t)d*16, a);
#pragma unroll
    for(int n=0;n<16;n++) a[n] = -__expf(a[n]);
    float st[16]; ld16(Hinit + (((size_t)b*NC_ + c)*DI + d)*16, st);
    float Dp = Dpar[d];
    int base = b*T_ + c*LCH;
#pragma unroll 2
    for(int t=0;t<LCH;t++){
        int bt = base + t;
        float dtv = dt[(size_t)bt*DI + d];
        float xhv = xh[(size_t)bt*DI + d];
        float bv[16]; ld16(bc + (size_t)bt*32, bv);
        float cv[16]; ld16(bc + (size_t)bt*32 + 16, cv);
        float dx = dtv*xhv;
        float y = 0.f;
#pragma unroll
        for(int n=0;n<16;n++){
            st[n] = __expf(dtv*a[n])*st[n] + dx*bv[n];
            y += st[n]*cv[n];
        }
        float zv = xz[(size_t)bt*DX + DI + d];
        y += Dp*xhv;
        y = y * zv * sigmoidf_(zv);
        unsigned short hh = f2bf(y);
        yhi[(size_t)bt*DI + d] = hh;
        ylo[(size_t)bt*DI + d] = f2bf(y - bf2f(hh));
    }
}

// out[bt] = dot(h[bt, :256], out_W)
__global__ void k_outw(const float* __restrict__ h, const float* __restrict__ ow,
                       float* __restrict__ out){
    int wv = threadIdx.x >> 6, lane = threadIdx.x & 63;
    int bt = blockIdx.x*4 + wv;
    float4 v = ((const float4*)(h + (size_t)bt*DM))[lane];
    float4 w = ((const float4*)ow)[lane];
    float s = v.x*w.x + v.y*w.y + v.z*w.z + v.w*w.w;
#pragma unroll
    for(int m=1;m<64;m<<=1) s += __shfl_xor(s,m);
    if(lane==0) out[bt] = s;
}

extern "C" void kernel_launch(void* const* d_in, const int* in_sizes, int n_in,
                              void* d_out, int out_size, void* d_ws, size_t ws_size,
                              hipStream_t stream){
    const float* x_src    = (const float*)d_in[0];
    const float* in_W     = (const float*)d_in[2];
    const float* norm_w   = (const float*)d_in[3];
    const float* norm_b   = (const float*)d_in[4];
    const float* inproj_W = (const float*)d_in[5];
    const float* conv_w   = (const float*)d_in[6];
    const float* conv_b   = (const float*)d_in[7];
    const float* xproj_W  = (const float*)d_in[8];
    const float* dtproj_W = (const float*)d_in[9];
    const float* dtproj_b = (const float*)d_in[10];
    const float* A_log    = (const float*)d_in[11];
    const float* D_param  = (const float*)d_in[12];
    const float* outproj_W= (const float*)d_in[13];
    const float* out_W    = (const float*)d_in[14];

    float* ws  = (float*)d_ws;
    float* h    = ws;                        // BT*DM
    float* res  = h    + (size_t)BT_*DM;     // BT*DM
    float* xz   = res  + (size_t)BT_*DM;     // BT*DX
    float* xh   = xz   + (size_t)BT_*DX;     // BT*DI
    float* bcb  = xh   + (size_t)BT_*DI;     // BT*32
    float* dtb  = bcb  + (size_t)BT_*32;     // BT*DI
    float* sdtb = dtb  + (size_t)BT_*DI;     // B*NC*DI
    float* Hbuf = sdtb + (size_t)B_*NC_*DI;  // B*NC*DI*16 = BT*DM floats
    unsigned short* us = (unsigned short*)(Hbuf + (size_t)BT_*DM);
    unsigned short* WhiIn  = us;                                  // NL*DX*DM
    unsigned short* WloIn  = WhiIn  + (size_t)NL*DX*DM;
    unsigned short* WhiOut = WloIn  + (size_t)NL*DX*DM;           // NL*DM*DI
    unsigned short* WloOut = WhiOut + (size_t)NL*DM*DI;
    unsigned short* hnhi   = WloOut + (size_t)NL*DM*DI;           // BT*DM
    unsigned short* hnlo   = hnhi   + (size_t)BT_*DM;
    unsigned short* yhi    = hnlo   + (size_t)BT_*DM;             // BT*DI
    unsigned short* ylo    = yhi    + (size_t)BT_*DI;
    float* Sbuf = h;   // dead during scan

    k_cvtW<<<(NL*DX*DM/4 + 255)/256, 256, 0, stream>>>(inproj_W,  WhiIn,  WloIn,  NL*DX*DM/4);
    k_cvtW<<<(NL*DM*DI/4 + 255)/256, 256, 0, stream>>>(outproj_W, WhiOut, WloOut, NL*DM*DI/4);
    k_ingemm<<<BT_*DM/256, 256, 0, stream>>>(x_src, in_W, h);
    for(int i=0;i<NL;i++){
        k_resln<<<BT_/4, 256, 0, stream>>>(h, res, hnhi, hnlo, norm_w + i*DM, norm_b + i*DM, i>0 ? 1 : 0);
        k_gemm_bf3<128,128><<<dim3(DX/128, BT_/128), 256, 0, stream>>>(
            hnhi, hnlo, WhiIn + (size_t)i*DX*DM, WloIn + (size_t)i*DX*DM, xz, BT_, DX, DM);
        k_conv<<<BT_*DI/256, 256, 0, stream>>>(xz, conv_w + i*DI*4, conv_b + i*DI, xh);
        k_xproj<<<BT_/16, 256, 0, stream>>>(xh, xproj_W + (size_t)i*NO_*DI,
                                            dtproj_W + (size_t)i*DI*DR_, dtproj_b + i*DI, bcb, dtb);
        k_scan1<<<dim3(DI/256, NC_, B_), 256, 0, stream>>>(dtb, xh, bcb, A_log + (size_t)i*DI*DS_, Sbuf, sdtb);
        k_scan2<<<B_*DI*DS_/256, 256, 0, stream>>>(Sbuf, sdtb, A_log + (size_t)i*DI*DS_, Hbuf);
        k_scan3<<<dim3(DI/256, NC_, B_), 256, 0, stream>>>(dtb, xh, xz, bcb, A_log + (size_t)i*DI*DS_,
                                                           D_param + i*DI, Hbuf, yhi, ylo);
        k_gemm_bf3<128,64><<<dim3(DM/64, BT_/128), 256, 0, stream>>>(
            yhi, ylo, WhiOut + (size_t)i*DM*DI, WloOut + (size_t)i*DM*DI, h, BT_, DM, DI);
    }
    k_outw<<<BT_/4, 256, 0, stream>>>(h, out_W, (float*)d_out);
}

// Round 4
// 752.487 us; speedup vs baseline: 4.0611x; 1.0663x over previous
//
#include <hip/hip_runtime.h>

#define B_   4
#define T_   2048
#define BT_  8192
#define INL  15
#define DM   256
#define DI   512
#define DX   1024
#define DS_  16
#define DR_  16
#define NO_  48
#define NL   4
#define NC_  64
#define LCH  32

typedef short bf16x8 __attribute__((ext_vector_type(8)));
typedef float f32x4  __attribute__((ext_vector_type(4)));

__device__ __forceinline__ float sigmoidf_(float x){ return 1.f/(1.f+__expf(-x)); }

__device__ __forceinline__ unsigned short f2bf(float x){
    union { float f; unsigned u; } v; v.f = x;
    unsigned r = (v.u + 0x7FFFu + ((v.u >> 16) & 1u)) >> 16;
    return (unsigned short)r;
}
__device__ __forceinline__ float bf2f(unsigned short h){
    union { unsigned u; float f; } v; v.u = ((unsigned)h) << 16;
    return v.f;
}

__device__ __forceinline__ void ld16(const float* __restrict__ p, float* v){
    const float4* q = (const float4*)p;
    float4 x0=q[0],x1=q[1],x2=q[2],x3=q[3];
    v[0]=x0.x; v[1]=x0.y; v[2]=x0.z; v[3]=x0.w;
    v[4]=x1.x; v[5]=x1.y; v[6]=x1.z; v[7]=x1.w;
    v[8]=x2.x; v[9]=x2.y; v[10]=x2.z; v[11]=x2.w;
    v[12]=x3.x; v[13]=x3.y; v[14]=x3.z; v[15]=x3.w;
}
__device__ __forceinline__ void st16(float* __restrict__ p, const float* v){
    float4* q = (float4*)p;
    q[0] = make_float4(v[0],v[1],v[2],v[3]);
    q[1] = make_float4(v[4],v[5],v[6],v[7]);
    q[2] = make_float4(v[8],v[9],v[10],v[11]);
    q[3] = make_float4(v[12],v[13],v[14],v[15]);
}

// convert fp32 array -> bf16 hi/lo split (4 elems/thread)
__global__ void k_cvtW(const float* __restrict__ W, unsigned short* __restrict__ hi,
                       unsigned short* __restrict__ lo, int n4){
    int g = blockIdx.x*256 + threadIdx.x;
    if(g >= n4) return;
    float4 v = ((const float4*)W)[g];
    ushort4 h, l;
    h.x = f2bf(v.x); l.x = f2bf(v.x - bf2f(h.x));
    h.y = f2bf(v.y); l.y = f2bf(v.y - bf2f(h.y));
    h.z = f2bf(v.z); l.z = f2bf(v.z - bf2f(h.z));
    h.w = f2bf(v.w); l.w = f2bf(v.w - bf2f(h.w));
    ((ushort4*)hi)[g] = h;
    ((ushort4*)lo)[g] = l;
}

// h[bt][m] = sum_k x[bt][k] * in_W[m][k]   (K=15)
__global__ void k_ingemm(const float* __restrict__ x, const float* __restrict__ W,
                         float* __restrict__ h){
    int g  = blockIdx.x*256 + threadIdx.x;
    int bt = g >> 8, m = g & 255;
    const float* xr = x + bt*INL;
    const float* wr = W + m*INL;
    float acc = 0.f;
#pragma unroll
    for(int k=0;k<INL;k++) acc += xr[k]*wr[k];
    h[g] = acc;
}

// res = h (+ res_prev); hn = LN(res)*w+b -> bf16 hi/lo. One wave per token.
__global__ void k_resln(const float* __restrict__ h, float* __restrict__ res,
                        unsigned short* __restrict__ hnhi, unsigned short* __restrict__ hnlo,
                        const float* __restrict__ w, const float* __restrict__ b, int addRes){
    int wv = threadIdx.x >> 6, lane = threadIdx.x & 63;
    int bt = blockIdx.x*4 + wv;
    float4 v = ((const float4*)(h + (size_t)bt*DM))[lane];
    if(addRes){
        float4 r = ((const float4*)(res + (size_t)bt*DM))[lane];
        v.x+=r.x; v.y+=r.y; v.z+=r.z; v.w+=r.w;
    }
    ((float4*)(res + (size_t)bt*DM))[lane] = v;
    float s  = v.x+v.y+v.z+v.w;
    float ss = v.x*v.x+v.y*v.y+v.z*v.z+v.w*v.w;
#pragma unroll
    for(int m=1;m<64;m<<=1){ s += __shfl_xor(s,m); ss += __shfl_xor(ss,m); }
    float mean = s*(1.f/DM);
    float var  = ss*(1.f/DM) - mean*mean;
    float inv  = rsqrtf(var + 1e-5f);
    float4 wt = ((const float4*)w)[lane];
    float4 bs = ((const float4*)b)[lane];
    float4 o;
    o.x = (v.x-mean)*inv*wt.x + bs.x;
    o.y = (v.y-mean)*inv*wt.y + bs.y;
    o.z = (v.z-mean)*inv*wt.z + bs.z;
    o.w = (v.w-mean)*inv*wt.w + bs.w;
    ushort4 hh, ll;
    hh.x = f2bf(o.x); ll.x = f2bf(o.x - bf2f(hh.x));
    hh.y = f2bf(o.y); ll.y = f2bf(o.y - bf2f(hh.y));
    hh.z = f2bf(o.z); ll.z = f2bf(o.z - bf2f(hh.z));
    hh.w = f2bf(o.w); ll.w = f2bf(o.w - bf2f(hh.w));
    ((ushort4*)(hnhi + (size_t)bt*DM))[lane] = hh;
    ((ushort4*)(hnlo + (size_t)bt*DM))[lane] = ll;
}

// C[M][N] = A[M][K] @ Bw[N][K]^T via bf16 MFMA, hi/lo 3-term split.
template<int BM,int BN>
__global__ void __launch_bounds__(256) k_gemm_bf3(
    const unsigned short* __restrict__ Ahi, const unsigned short* __restrict__ Alo,
    const unsigned short* __restrict__ Bhi, const unsigned short* __restrict__ Blo,
    float* __restrict__ C, int M, int N, int K)
{
    constexpr int LDP = 40;
    constexpr int WM = BM/2, WN = BN/2;
    constexpr int MI_ = WM/16, NI_ = WN/16;
    __shared__ unsigned short sAh[BM*LDP], sAl[BM*LDP], sBh[BN*LDP], sBl[BN*LDP];
    int tid  = threadIdx.x;
    int wave = tid >> 6, lane = tid & 63;
    int wm0  = (wave >> 1) * WM, wn0 = (wave & 1) * WN;
    int m0   = blockIdx.y * BM, n0 = blockIdx.x * BN;
    int lr   = lane & 15;
    int kq   = (lane >> 4) * 8;
    int quad4 = (lane >> 4) * 4;

    f32x4 acc[MI_][NI_];
#pragma unroll
    for(int i=0;i<MI_;i++)
#pragma unroll
        for(int j=0;j<NI_;j++) acc[i][j] = (f32x4){0.f,0.f,0.f,0.f};

    for(int k0=0;k0<K;k0+=32){
#pragma unroll
        for(int i=tid;i<BM*4;i+=256){
            int r = i>>2, cg = (i&3)*8;
            size_t go = (size_t)(m0+r)*K + k0 + cg;
            *(float4*)(&sAh[r*LDP + cg]) = *(const float4*)(Ahi + go);
            *(float4*)(&sAl[r*LDP + cg]) = *(const float4*)(Alo + go);
        }
#pragma unroll
        for(int i=tid;i<BN*4;i+=256){
            int r = i>>2, cg = (i&3)*8;
            size_t go = (size_t)(n0+r)*K + k0 + cg;
            *(float4*)(&sBh[r*LDP + cg]) = *(const float4*)(Bhi + go);
            *(float4*)(&sBl[r*LDP + cg]) = *(const float4*)(Blo + go);
        }
        __syncthreads();
        bf16x8 ah[MI_], al[MI_], bh[NI_], bl[NI_];
#pragma unroll
        for(int mi=0;mi<MI_;mi++){
            int ro = (wm0 + mi*16 + lr)*LDP + kq;
            ah[mi] = *(const bf16x8*)(&sAh[ro]);
            al[mi] = *(const bf16x8*)(&sAl[ro]);
        }
#pragma unroll
        for(int ni=0;ni<NI_;ni++){
            int ro = (wn0 + ni*16 + lr)*LDP + kq;
            bh[ni] = *(const bf16x8*)(&sBh[ro]);
            bl[ni] = *(const bf16x8*)(&sBl[ro]);
        }
#pragma unroll
        for(int mi=0;mi<MI_;mi++)
#pragma unroll
            for(int ni=0;ni<NI_;ni++){
                acc[mi][ni] = __builtin_amdgcn_mfma_f32_16x16x32_bf16(ah[mi], bh[ni], acc[mi][ni], 0,0,0);
                acc[mi][ni] = __builtin_amdgcn_mfma_f32_16x16x32_bf16(ah[mi], bl[ni], acc[mi][ni], 0,0,0);
                acc[mi][ni] = __builtin_amdgcn_mfma_f32_16x16x32_bf16(al[mi], bh[ni], acc[mi][ni], 0,0,0);
            }
        __syncthreads();
    }
#pragma unroll
    for(int mi=0;mi<MI_;mi++)
#pragma unroll
        for(int ni=0;ni<NI_;ni++){
            int col = n0 + wn0 + ni*16 + lr;
#pragma unroll
            for(int r=0;r<4;r++){
                int row = m0 + wm0 + mi*16 + quad4 + r;
                C[(size_t)row*N + col] = acc[mi][ni][r];
            }
        }
}

// depthwise causal conv(4) + bias + SiLU; fp32 out + bf16 hi/lo out
__global__ void k_conv(const float* __restrict__ xz, const float* __restrict__ cw,
                       const float* __restrict__ cb, float* __restrict__ xh,
                       unsigned short* __restrict__ xhhi, unsigned short* __restrict__ xhlo){
    int g  = blockIdx.x*256 + threadIdx.x;
    int bt = g >> 9, d = g & 511;
    int t  = bt & (T_-1);
    const float* wr = cw + d*4;
    float acc = cb[d];
#pragma unroll
    for(int k=0;k<4;k++){
        int tt = t - 3 + k;
        if(tt >= 0) acc += xz[(size_t)(bt-3+k)*DX + d] * wr[k];
    }
    float v = acc * sigmoidf_(acc);
    xh[g] = v;
    unsigned short hh = f2bf(v);
    xhhi[g] = hh;
    xhlo[g] = f2bf(v - bf2f(hh));
}

// xproj via MFMA: dbl = xh @ xpW^T (M=BT, N=48, K=512). BM=64, 4 waves x 16 rows.
// cols 0..15 -> dlb (fp32), cols 16..47 -> bc (fp32).
__global__ void __launch_bounds__(256) k_xprojA(
    const unsigned short* __restrict__ Ahi, const unsigned short* __restrict__ Alo,
    const unsigned short* __restrict__ Bhi, const unsigned short* __restrict__ Blo,
    float* __restrict__ bc, float* __restrict__ dlb)
{
    constexpr int LDP = 40;
    __shared__ unsigned short sAh[64*LDP], sAl[64*LDP], sBh[48*LDP], sBl[48*LDP];
    int tid = threadIdx.x;
    int wave = tid >> 6, lane = tid & 63;
    int wm0 = wave * 16;
    int m0  = blockIdx.x * 64;
    int lr  = lane & 15;
    int kq  = (lane >> 4) * 8;
    int quad4 = (lane >> 4) * 4;

    f32x4 acc[3];
#pragma unroll
    for(int j=0;j<3;j++) acc[j] = (f32x4){0.f,0.f,0.f,0.f};

    for(int k0=0;k0<DI;k0+=32){
#pragma unroll
        for(int i=tid;i<64*4;i+=256){
            int r = i>>2, cg = (i&3)*8;
            size_t go = (size_t)(m0+r)*DI + k0 + cg;
            *(float4*)(&sAh[r*LDP + cg]) = *(const float4*)(Ahi + go);
            *(float4*)(&sAl[r*LDP + cg]) = *(const float4*)(Alo + go);
        }
        if(tid < 48*4){
            int r = tid>>2, cg = (tid&3)*8;
            size_t go = (size_t)r*DI + k0 + cg;
            *(float4*)(&sBh[r*LDP + cg]) = *(const float4*)(Bhi + go);
            *(float4*)(&sBl[r*LDP + cg]) = *(const float4*)(Blo + go);
        }
        __syncthreads();
        bf16x8 ah, al;
        {
            int ro = (wm0 + lr)*LDP + kq;
            ah = *(const bf16x8*)(&sAh[ro]);
            al = *(const bf16x8*)(&sAl[ro]);
        }
#pragma unroll
        for(int ni=0;ni<3;ni++){
            int ro = (ni*16 + lr)*LDP + kq;
            bf16x8 bh = *(const bf16x8*)(&sBh[ro]);
            bf16x8 bl = *(const bf16x8*)(&sBl[ro]);
            acc[ni] = __builtin_amdgcn_mfma_f32_16x16x32_bf16(ah, bh, acc[ni], 0,0,0);
            acc[ni] = __builtin_amdgcn_mfma_f32_16x16x32_bf16(ah, bl, acc[ni], 0,0,0);
            acc[ni] = __builtin_amdgcn_mfma_f32_16x16x32_bf16(al, bh, acc[ni], 0,0,0);
        }
        __syncthreads();
    }
#pragma unroll
    for(int r=0;r<4;r++){
        int row = m0 + wm0 + quad4 + r;
        dlb[(size_t)row*16 + lr] = acc[0][r];
        bc[(size_t)row*32 + lr]      = acc[1][r];
        bc[(size_t)row*32 + 16 + lr] = acc[2][r];
    }
}

// dtproj + softplus: dt[bt][d] = softplus(sum_r dl[bt][r]*dtW[d][r] + dtb[d])
__global__ void k_dtproj(const float* __restrict__ dlb, const float* __restrict__ dtW,
                         const float* __restrict__ dtbias, float* __restrict__ dtO){
    __shared__ float dls[16][17];
    int bt0 = blockIdx.x*16;
    dls[threadIdx.x>>4][threadIdx.x&15] = dlb[(size_t)(bt0 + (threadIdx.x>>4))*16 + (threadIdx.x&15)];
    __syncthreads();
    int tok = threadIdx.x >> 4, dsl = threadIdx.x & 15;
#pragma unroll
    for(int jj=0;jj<32;jj++){
        int d = jj*16 + dsl;
        const float* wr = dtW + d*DR_;
        float acc = dtbias[d];
#pragma unroll
        for(int r=0;r<16;r++) acc += dls[tok][r]*wr[r];
        float sp = fmaxf(acc,0.f) + log1pf(__expf(-fabsf(acc)));
        dtO[(size_t)(bt0+tok)*DI + d] = sp;
    }
}

// ---- chunk-parallel scan pass 1 ----
__global__ void __launch_bounds__(256) k_scan1(const float* __restrict__ dt,
    const float* __restrict__ xh, const float* __restrict__ bc,
    const float* __restrict__ A_log, float* __restrict__ S, float* __restrict__ sdt){
    int d = blockIdx.x*256 + threadIdx.x;
    int c = blockIdx.y, b = blockIdx.z;
    float a[16]; ld16(A_log + (size_t)d*16, a);
#pragma unroll
    for(int n=0;n<16;n++) a[n] = -__expf(a[n]);
    float st[16];
#pragma unroll
    for(int n=0;n<16;n++) st[n] = 0.f;
    float sd = 0.f;
    int base = b*T_ + c*LCH;
#pragma unroll 2
    for(int t=0;t<LCH;t++){
        int bt = base + t;
        float dtv = dt[(size_t)bt*DI + d];
        float xhv = xh[(size_t)bt*DI + d];
        float bv[16]; ld16(bc + (size_t)bt*32, bv);
        float dx = dtv*xhv;
        sd += dtv;
#pragma unroll
        for(int n=0;n<16;n++) st[n] = __expf(dtv*a[n])*st[n] + dx*bv[n];
    }
    st16(S + (((size_t)b*NC_ + c)*DI + d)*16, st);
    sdt[((size_t)b*NC_ + c)*DI + d] = sd;
}

// ---- pass 2: inter-chunk scan ----
__global__ void k_scan2(const float* __restrict__ S, const float* __restrict__ sdt,
                        const float* __restrict__ A_log, float* __restrict__ Hinit){
    int g = blockIdx.x*256 + threadIdx.x;
    int b = g >> 13;
    int dn = g & 8191;
    int d = dn >> 4;
    float a = -__expf(A_log[dn]);
    float H = 0.f;
    for(int c=0;c<NC_;c++){
        size_t o = ((size_t)(b*NC_ + c))*8192 + dn;
        Hinit[o] = H;
        float sd = sdt[(size_t)(b*NC_ + c)*DI + d];
        H = __expf(sd*a)*H + S[o];
    }
}

// ---- pass 3: replay + gate; writes ys as bf16 hi/lo ----
__global__ void __launch_bounds__(256) k_scan3(const float* __restrict__ dt,
    const float* __restrict__ xh, const float* __restrict__ xz,
    const float* __restrict__ bc, const float* __restrict__ A_log,
    const float* __restrict__ Dpar, const float* __restrict__ Hinit,
    unsigned short* __restrict__ yhi, unsigned short* __restrict__ ylo){
    int d = blockIdx.x*256 + threadIdx.x;
    int c = blockIdx.y, b = blockIdx.z;
    float a[16]; ld16(A_log + (size_t)d*16, a);
#pragma unroll
    for(int n=0;n<16;n++) a[n] = -__expf(a[n]);
    float st[16]; ld16(Hinit + (((size_t)b*NC_ + c)*DI + d)*16, st);
    float Dp = Dpar[d];
    int base = b*T_ + c*LCH;
#pragma unroll 2
    for(int t=0;t<LCH;t++){
        int bt = base + t;
        float dtv = dt[(size_t)bt*DI + d];
        float xhv = xh[(size_t)bt*DI + d];
        float bv[16]; ld16(bc + (size_t)bt*32, bv);
        float cv[16]; ld16(bc + (size_t)bt*32 + 16, cv);
        float dx = dtv*xhv;
        float y = 0.f;
#pragma unroll
        for(int n=0;n<16;n++){
            st[n] = __expf(dtv*a[n])*st[n] + dx*bv[n];
            y += st[n]*cv[n];
        }
        float zv = xz[(size_t)bt*DX + DI + d];
        y += Dp*xhv;
        y = y * zv * sigmoidf_(zv);
        unsigned short hh = f2bf(y);
        yhi[(size_t)bt*DI + d] = hh;
        ylo[(size_t)bt*DI + d] = f2bf(y - bf2f(hh));
    }
}

// out[bt] = dot(h[bt, :256], out_W)
__global__ void k_outw(const float* __restrict__ h, const float* __restrict__ ow,
                       float* __restrict__ out){
    int wv = threadIdx.x >> 6, lane = threadIdx.x & 63;
    int bt = blockIdx.x*4 + wv;
    float4 v = ((const float4*)(h + (size_t)bt*DM))[lane];
    float4 w = ((const float4*)ow)[lane];
    float s = v.x*w.x + v.y*w.y + v.z*w.z + v.w*w.w;
#pragma unroll
    for(int m=1;m<64;m<<=1) s += __shfl_xor(s,m);
    if(lane==0) out[bt] = s;
}

extern "C" void kernel_launch(void* const* d_in, const int* in_sizes, int n_in,
                              void* d_out, int out_size, void* d_ws, size_t ws_size,
                              hipStream_t stream){
    const float* x_src    = (const float*)d_in[0];
    const float* in_W     = (const float*)d_in[2];
    const float* norm_w   = (const float*)d_in[3];
    const float* norm_b   = (const float*)d_in[4];
    const float* inproj_W = (const float*)d_in[5];
    const float* conv_w   = (const float*)d_in[6];
    const float* conv_b   = (const float*)d_in[7];
    const float* xproj_W  = (const float*)d_in[8];
    const float* dtproj_W = (const float*)d_in[9];
    const float* dtproj_b = (const float*)d_in[10];
    const float* A_log    = (const float*)d_in[11];
    const float* D_param  = (const float*)d_in[12];
    const float* outproj_W= (const float*)d_in[13];
    const float* out_W    = (const float*)d_in[14];

    float* ws  = (float*)d_ws;
    float* h    = ws;                        // BT*DM
    float* res  = h    + (size_t)BT_*DM;     // BT*DM
    float* xz   = res  + (size_t)BT_*DM;     // BT*DX
    float* xh   = xz   + (size_t)BT_*DX;     // BT*DI
    float* bcb  = xh   + (size_t)BT_*DI;     // BT*32
    float* dtb  = bcb  + (size_t)BT_*32;     // BT*DI
    float* sdtb = dtb  + (size_t)BT_*DI;     // B*NC*DI
    float* dlb  = sdtb + (size_t)B_*NC_*DI;  // BT*16
    float* Hbuf = dlb  + (size_t)BT_*16;     // BT*DM floats
    unsigned short* us = (unsigned short*)(Hbuf + (size_t)BT_*DM);
    unsigned short* WhiIn  = us;                                  // NL*DX*DM
    unsigned short* WloIn  = WhiIn  + (size_t)NL*DX*DM;
    unsigned short* WhiOut = WloIn  + (size_t)NL*DX*DM;           // NL*DM*DI
    unsigned short* WloOut = WhiOut + (size_t)NL*DM*DI;
    unsigned short* WhiXp  = WloOut + (size_t)NL*DM*DI;           // NL*NO*DI
    unsigned short* WloXp  = WhiXp  + (size_t)NL*NO_*DI;
    unsigned short* hnhi   = WloXp  + (size_t)NL*NO_*DI;          // BT*DM
    unsigned short* hnlo   = hnhi   + (size_t)BT_*DM;
    unsigned short* yhi    = hnlo   + (size_t)BT_*DM;             // BT*DI (also xh bf16: dead windows don't overlap)
    unsigned short* ylo    = yhi    + (size_t)BT_*DI;
    float* Sbuf = h;   // dead during scan

    k_cvtW<<<(NL*DX*DM/4 + 255)/256, 256, 0, stream>>>(inproj_W,  WhiIn,  WloIn,  NL*DX*DM/4);
    k_cvtW<<<(NL*DM*DI/4 + 255)/256, 256, 0, stream>>>(outproj_W, WhiOut, WloOut, NL*DM*DI/4);
    k_cvtW<<<(NL*NO_*DI/4 + 255)/256, 256, 0, stream>>>(xproj_W, WhiXp, WloXp, NL*NO_*DI/4);
    k_ingemm<<<BT_*DM/256, 256, 0, stream>>>(x_src, in_W, h);
    for(int i=0;i<NL;i++){
        k_resln<<<BT_/4, 256, 0, stream>>>(h, res, hnhi, hnlo, norm_w + i*DM, norm_b + i*DM, i>0 ? 1 : 0);
        k_gemm_bf3<128,128><<<dim3(DX/128, BT_/128), 256, 0, stream>>>(
            hnhi, hnlo, WhiIn + (size_t)i*DX*DM, WloIn + (size_t)i*DX*DM, xz, BT_, DX, DM);
        // conv writes xh bf16 into yhi/ylo (dead until scan3 overwrites; xproj consumes first)
        k_conv<<<BT_*DI/256, 256, 0, stream>>>(xz, conv_w + i*DI*4, conv_b + i*DI, xh, yhi, ylo);
        k_xprojA<<<BT_/64, 256, 0, stream>>>(yhi, ylo, WhiXp + (size_t)i*NO_*DI, WloXp + (size_t)i*NO_*DI,
                                             bcb, dlb);
        k_dtproj<<<BT_/16, 256, 0, stream>>>(dlb, dtproj_W + (size_t)i*DI*DR_, dtproj_b + i*DI, dtb);
        k_scan1<<<dim3(DI/256, NC_, B_), 256, 0, stream>>>(dtb, xh, bcb, A_log + (size_t)i*DI*DS_, Sbuf, sdtb);
        k_scan2<<<B_*DI*DS_/256, 256, 0, stream>>>(Sbuf, sdtb, A_log + (size_t)i*DI*DS_, Hbuf);
        k_scan3<<<dim3(DI/256, NC_, B_), 256, 0, stream>>>(dtb, xh, xz, bcb, A_log + (size_t)i*DI*DS_,
                                                           D_param + i*DI, Hbuf, yhi, ylo);
        k_gemm_bf3<128,64><<<dim3(DM/64, BT_/128), 256, 0, stream>>>(
            yhi, ylo, WhiOut + (size_t)i*DM*DI, WloOut + (size_t)i*DM*DI, h, BT_, DM, DI);
    }
    k_outw<<<BT_/4, 256, 0, stream>>>(h, out_W, (float*)d_out);
}

// Round 5
// 679.281 us; speedup vs baseline: 4.4987x; 1.1078x over previous
//
#include <hip/hip_runtime.h>

#define B_   4
#define T_   2048
#define BT_  8192
#define INL  15
#define DM   256
#define DI   512
#define DX   1024
#define DS_  16
#define DR_  16
#define NO_  48
#define NL   4
#define NC_  64
#define LCH  32

typedef short bf16x8 __attribute__((ext_vector_type(8)));
typedef float f32x4  __attribute__((ext_vector_type(4)));

__device__ __forceinline__ float sigmoidf_(float x){ return 1.f/(1.f+__expf(-x)); }

__device__ __forceinline__ unsigned short f2bf(float x){
    union { float f; unsigned u; } v; v.f = x;
    unsigned r = (v.u + 0x7FFFu + ((v.u >> 16) & 1u)) >> 16;
    return (unsigned short)r;
}
__device__ __forceinline__ float bf2f(unsigned short h){
    union { unsigned u; float f; } v; v.u = ((unsigned)h) << 16;
    return v.f;
}

__device__ __forceinline__ void ld16(const float* __restrict__ p, float* v){
    const float4* q = (const float4*)p;
    float4 x0=q[0],x1=q[1],x2=q[2],x3=q[3];
    v[0]=x0.x; v[1]=x0.y; v[2]=x0.z; v[3]=x0.w;
    v[4]=x1.x; v[5]=x1.y; v[6]=x1.z; v[7]=x1.w;
    v[8]=x2.x; v[9]=x2.y; v[10]=x2.z; v[11]=x2.w;
    v[12]=x3.x; v[13]=x3.y; v[14]=x3.z; v[15]=x3.w;
}
__device__ __forceinline__ void st16(float* __restrict__ p, const float* v){
    float4* q = (float4*)p;
    q[0] = make_float4(v[0],v[1],v[2],v[3]);
    q[1] = make_float4(v[4],v[5],v[6],v[7]);
    q[2] = make_float4(v[8],v[9],v[10],v[11]);
    q[3] = make_float4(v[12],v[13],v[14],v[15]);
}

// convert fp32 array -> bf16 hi/lo split
__global__ void k_cvtW(const float* __restrict__ W, unsigned short* __restrict__ hi,
                       unsigned short* __restrict__ lo, int n4){
    int g = blockIdx.x*256 + threadIdx.x;
    if(g >= n4) return;
    float4 v = ((const float4*)W)[g];
    ushort4 h, l;
    h.x = f2bf(v.x); l.x = f2bf(v.x - bf2f(h.x));
    h.y = f2bf(v.y); l.y = f2bf(v.y - bf2f(h.y));
    h.z = f2bf(v.z); l.z = f2bf(v.z - bf2f(h.z));
    h.w = f2bf(v.w); l.w = f2bf(v.w - bf2f(h.w));
    ((ushort4*)hi)[g] = h;
    ((ushort4*)lo)[g] = l;
}

// h[bt][m] = sum_k x[bt][k] * in_W[m][k]
__global__ void k_ingemm(const float* __restrict__ x, const float* __restrict__ W,
                         float* __restrict__ h){
    int g  = blockIdx.x*256 + threadIdx.x;
    int bt = g >> 8, m = g & 255;
    const float* xr = x + bt*INL;
    const float* wr = W + m*INL;
    float acc = 0.f;
#pragma unroll
    for(int k=0;k<INL;k++) acc += xr[k]*wr[k];
    h[g] = acc;
}

// res = h (+ res_prev); hn = LN(res)*w+b -> bf16 hi/lo
__global__ void k_resln(const float* __restrict__ h, float* __restrict__ res,
                        unsigned short* __restrict__ hnhi, unsigned short* __restrict__ hnlo,
                        const float* __restrict__ w, const float* __restrict__ b, int addRes){
    int wv = threadIdx.x >> 6, lane = threadIdx.x & 63;
    int bt = blockIdx.x*4 + wv;
    float4 v = ((const float4*)(h + (size_t)bt*DM))[lane];
    if(addRes){
        float4 r = ((const float4*)(res + (size_t)bt*DM))[lane];
        v.x+=r.x; v.y+=r.y; v.z+=r.z; v.w+=r.w;
    }
    ((float4*)(res + (size_t)bt*DM))[lane] = v;
    float s  = v.x+v.y+v.z+v.w;
    float ss = v.x*v.x+v.y*v.y+v.z*v.z+v.w*v.w;
#pragma unroll
    for(int m=1;m<64;m<<=1){ s += __shfl_xor(s,m); ss += __shfl_xor(ss,m); }
    float mean = s*(1.f/DM);
    float var  = ss*(1.f/DM) - mean*mean;
    float inv  = rsqrtf(var + 1e-5f);
    float4 wt = ((const float4*)w)[lane];
    float4 bs = ((const float4*)b)[lane];
    float4 o;
    o.x = (v.x-mean)*inv*wt.x + bs.x;
    o.y = (v.y-mean)*inv*wt.y + bs.y;
    o.z = (v.z-mean)*inv*wt.z + bs.z;
    o.w = (v.w-mean)*inv*wt.w + bs.w;
    ushort4 hh, ll;
    hh.x = f2bf(o.x); ll.x = f2bf(o.x - bf2f(hh.x));
    hh.y = f2bf(o.y); ll.y = f2bf(o.y - bf2f(hh.y));
    hh.z = f2bf(o.z); ll.z = f2bf(o.z - bf2f(hh.z));
    hh.w = f2bf(o.w); ll.w = f2bf(o.w - bf2f(hh.w));
    ((ushort4*)(hnhi + (size_t)bt*DM))[lane] = hh;
    ((ushort4*)(hnlo + (size_t)bt*DM))[lane] = ll;
}

// C[M][N] = A[M][K] @ Bw[N][K]^T via bf16 MFMA, hi/lo 3-term split (inproj)
template<int BM,int BN>
__global__ void __launch_bounds__(256) k_gemm_bf3(
    const unsigned short* __restrict__ Ahi, const unsigned short* __restrict__ Alo,
    const unsigned short* __restrict__ Bhi, const unsigned short* __restrict__ Blo,
    float* __restrict__ C, int M, int N, int K)
{
    constexpr int LDP = 40;
    constexpr int WM = BM/2, WN = BN/2;
    constexpr int MI_ = WM/16, NI_ = WN/16;
    __shared__ unsigned short sAh[BM*LDP], sAl[BM*LDP], sBh[BN*LDP], sBl[BN*LDP];
    int tid  = threadIdx.x;
    int wave = tid >> 6, lane = tid & 63;
    int wm0  = (wave >> 1) * WM, wn0 = (wave & 1) * WN;
    int m0   = blockIdx.y * BM, n0 = blockIdx.x * BN;
    int lr   = lane & 15;
    int kq   = (lane >> 4) * 8;
    int quad4 = (lane >> 4) * 4;

    f32x4 acc[MI_][NI_];
#pragma unroll
    for(int i=0;i<MI_;i++)
#pragma unroll
        for(int j=0;j<NI_;j++) acc[i][j] = (f32x4){0.f,0.f,0.f,0.f};

    for(int k0=0;k0<K;k0+=32){
#pragma unroll
        for(int i=tid;i<BM*4;i+=256){
            int r = i>>2, cg = (i&3)*8;
            size_t go = (size_t)(m0+r)*K + k0 + cg;
            *(float4*)(&sAh[r*LDP + cg]) = *(const float4*)(Ahi + go);
            *(float4*)(&sAl[r*LDP + cg]) = *(const float4*)(Alo + go);
        }
#pragma unroll
        for(int i=tid;i<BN*4;i+=256){
            int r = i>>2, cg = (i&3)*8;
            size_t go = (size_t)(n0+r)*K + k0 + cg;
            *(float4*)(&sBh[r*LDP + cg]) = *(const float4*)(Bhi + go);
            *(float4*)(&sBl[r*LDP + cg]) = *(const float4*)(Blo + go);
        }
        __syncthreads();
        bf16x8 ah[MI_], al[MI_], bh[NI_], bl[NI_];
#pragma unroll
        for(int mi=0;mi<MI_;mi++){
            int ro = (wm0 + mi*16 + lr)*LDP + kq;
            ah[mi] = *(const bf16x8*)(&sAh[ro]);
            al[mi] = *(const bf16x8*)(&sAl[ro]);
        }
#pragma unroll
        for(int ni=0;ni<NI_;ni++){
            int ro = (wn0 + ni*16 + lr)*LDP + kq;
            bh[ni] = *(const bf16x8*)(&sBh[ro]);
            bl[ni] = *(const bf16x8*)(&sBl[ro]);
        }
#pragma unroll
        for(int mi=0;mi<MI_;mi++)
#pragma unroll
            for(int ni=0;ni<NI_;ni++){
                acc[mi][ni] = __builtin_amdgcn_mfma_f32_16x16x32_bf16(ah[mi], bh[ni], acc[mi][ni], 0,0,0);
                acc[mi][ni] = __builtin_amdgcn_mfma_f32_16x16x32_bf16(ah[mi], bl[ni], acc[mi][ni], 0,0,0);
                acc[mi][ni] = __builtin_amdgcn_mfma_f32_16x16x32_bf16(al[mi], bh[ni], acc[mi][ni], 0,0,0);
            }
        __syncthreads();
    }
#pragma unroll
    for(int mi=0;mi<MI_;mi++)
#pragma unroll
        for(int ni=0;ni<NI_;ni++){
            int col = n0 + wn0 + ni*16 + lr;
#pragma unroll
            for(int r=0;r<4;r++){
                int row = m0 + wm0 + mi*16 + quad4 + r;
                C[(size_t)row*N + col] = acc[mi][ni][r];
            }
        }
}

// ---- fused: conv+SiLU -> xh | xproj MFMA -> bc | dtproj+softplus -> dt | scan pass-1 -> S,sdt ----
// One block per 32-token chunk (256 threads, 4 waves). xh bf16 lives only in LDS.
__global__ void __launch_bounds__(256) k_convxp(
    const float* __restrict__ xz, const float* __restrict__ cw, const float* __restrict__ cb,
    const unsigned short* __restrict__ Bhi, const unsigned short* __restrict__ Blo,
    const float* __restrict__ dtW, const float* __restrict__ dtbias,
    const float* __restrict__ A_log,
    float* __restrict__ xh, float* __restrict__ bc, float* __restrict__ dtO,
    float* __restrict__ S, float* __restrict__ sdt)
{
    __shared__ __align__(16) char smem[43520];
    unsigned short* sAh = (unsigned short*)smem;     // 32*136 shorts
    unsigned short* sAl = sAh + 32*136;
    unsigned short* sBh = sAl + 32*136;              // 48*136 shorts
    unsigned short* sBl = sBh + 48*136;
    float* dls  = (float*)smem;                      // 32*17 floats (phase 2, reuses sA)
    float* sdtW = dls + 32*17;                       // 512*17 floats

    int tid = threadIdx.x;
    int wave = tid >> 6, lane = tid & 63;
    int lr = lane & 15, kq = (lane>>4)*8, quad4 = (lane>>4)*4;
    int m0 = blockIdx.x * 32;
    int tp = tid >> 7;           // token half (0: t 0..15, 1: t 16..31)
    int cI = tid & 127;          // col within 128-wide K chunk
    bool mask0 = ((m0 & (T_-1)) == 0) && (tp == 0);

    int mi  = wave & 1;
    int niP = (wave < 2) ? 0 : 2;
    f32x4 accP = {0,0,0,0}, accQ = {0,0,0,0};

    for(int kc=0;kc<4;kc++){
        int d = kc*128 + cI;
        float4 w4 = *(const float4*)(cw + d*4);
        float bias = cb[d];
        float xv[19];
        int rbase = m0 + tp*16 - 3;
#pragma unroll
        for(int j=0;j<19;j++)
            xv[j] = (mask0 && j<3) ? 0.f : xz[(size_t)(rbase+j)*DX + d];
        for(int i=tid;i<768;i+=256){
            int r = i>>4, cc = (i&15)*8;
            size_t go = (size_t)r*DI + kc*128 + cc;
            *(float4*)(&sBh[r*136 + cc]) = *(const float4*)(Bhi + go);
            *(float4*)(&sBl[r*136 + cc]) = *(const float4*)(Blo + go);
        }
#pragma unroll
        for(int tt=0;tt<16;tt++){
            int t = tp*16 + tt;
            float a = bias + w4.x*xv[tt] + w4.y*xv[tt+1] + w4.z*xv[tt+2] + w4.w*xv[tt+3];
            float v = a * sigmoidf_(a);
            xh[(size_t)(m0+t)*DI + d] = v;
            unsigned short hh = f2bf(v);
            sAh[t*136 + cI] = hh;
            sAl[t*136 + cI] = f2bf(v - bf2f(hh));
        }
        __syncthreads();
#pragma unroll
        for(int ks=0;ks<4;ks++){
            int ao = (mi*16 + lr)*136 + ks*32 + kq;
            bf16x8 ah = *(const bf16x8*)(&sAh[ao]);
            bf16x8 al = *(const bf16x8*)(&sAl[ao]);
            int boP = (niP*16 + lr)*136 + ks*32 + kq;
            bf16x8 bh = *(const bf16x8*)(&sBh[boP]);
            bf16x8 bl = *(const bf16x8*)(&sBl[boP]);
            accP = __builtin_amdgcn_mfma_f32_16x16x32_bf16(ah, bh, accP, 0,0,0);
            accP = __builtin_amdgcn_mfma_f32_16x16x32_bf16(ah, bl, accP, 0,0,0);
            accP = __builtin_amdgcn_mfma_f32_16x16x32_bf16(al, bh, accP, 0,0,0);
            if(wave < 2){
                int boQ = (16 + lr)*136 + ks*32 + kq;
                bf16x8 bh2 = *(const bf16x8*)(&sBh[boQ]);
                bf16x8 bl2 = *(const bf16x8*)(&sBl[boQ]);
                accQ = __builtin_amdgcn_mfma_f32_16x16x32_bf16(ah, bh2, accQ, 0,0,0);
                accQ = __builtin_amdgcn_mfma_f32_16x16x32_bf16(ah, bl2, accQ, 0,0,0);
                accQ = __builtin_amdgcn_mfma_f32_16x16x32_bf16(al, bh2, accQ, 0,0,0);
            }
        }
        __syncthreads();
    }
    // epilogue: dl (rank cols) -> LDS, B/C cols -> bc global
    if(wave < 2){
#pragma unroll
        for(int r=0;r<4;r++){
            dls[(mi*16 + quad4 + r)*17 + lr] = accP[r];
            bc[(size_t)(m0 + mi*16 + quad4 + r)*32 + lr] = accQ[r];
        }
    } else {
#pragma unroll
        for(int r=0;r<4;r++)
            bc[(size_t)(m0 + mi*16 + quad4 + r)*32 + 16 + lr] = accP[r];
    }
    // stage dtW padded (pitch 17 breaks stride-16 bank conflict)
    for(int i=tid;i<DI*16;i+=256)
        sdtW[(i>>4)*17 + (i&15)] = dtW[i];
    __syncthreads();

    int b = m0 >> 11, c = (m0 >> 5) & (NC_-1);
#pragma unroll
    for(int j=0;j<2;j++){
        int d = j*256 + tid;
        // dtproj + softplus, keep dt in regs
        float wr_[16];
#pragma unroll
        for(int r=0;r<16;r++) wr_[r] = sdtW[d*17 + r];
        float bsv = dtbias[d];
        float dtreg[32];
#pragma unroll
        for(int t=0;t<32;t++){
            float acc = bsv;
#pragma unroll
            for(int r=0;r<16;r++) acc += dls[t*17 + r]*wr_[r];
            float sp = fmaxf(acc,0.f) + log1pf(__expf(-fabsf(acc)));
            dtreg[t] = sp;
            dtO[(size_t)(m0+t)*DI + d] = sp;
        }
        // scan pass-1 for this d (reads back block-local xh/bc via L1/L2)
        float a_[16]; ld16(A_log + (size_t)d*16, a_);
#pragma unroll
        for(int n=0;n<16;n++) a_[n] = -__expf(a_[n]);
        float st_[16];
#pragma unroll
        for(int n=0;n<16;n++) st_[n] = 0.f;
        float sd = 0.f;
#pragma unroll 4
        for(int t=0;t<32;t++){
            float dtv = dtreg[t];
            float xhv = xh[(size_t)(m0+t)*DI + d];
            float bv[16]; ld16(bc + (size_t)(m0+t)*32, bv);
            float dx = dtv*xhv;
            sd += dtv;
#pragma unroll
            for(int n=0;n<16;n++) st_[n] = __expf(dtv*a_[n])*st_[n] + dx*bv[n];
        }
        st16(S + (((size_t)b*NC_ + c)*DI + d)*16, st_);
        sdt[((size_t)b*NC_ + c)*DI + d] = sd;
    }
}

// ---- pass 2: inter-chunk scan ----
__global__ void k_scan2(const float* __restrict__ S, const float* __restrict__ sdt,
                        const float* __restrict__ A_log, float* __restrict__ Hinit){
    int g = blockIdx.x*256 + threadIdx.x;
    int b = g >> 13;
    int dn = g & 8191;
    int d = dn >> 4;
    float a = -__expf(A_log[dn]);
    float H = 0.f;
    for(int c=0;c<NC_;c++){
        size_t o = ((size_t)(b*NC_ + c))*8192 + dn;
        Hinit[o] = H;
        float sd = sdt[(size_t)(b*NC_ + c)*DI + d];
        H = __expf(sd*a)*H + S[o];
    }
}

// ---- fused: scan pass-3 replay + gate + outproj MFMA -> h. y never hits HBM. ----
// grid (NC, B), 512 threads (8 waves). y tile 32x512 as bf16 hi/lo in LDS (pitch 520).
__global__ void __launch_bounds__(512) k_scan3o(
    const float* __restrict__ dt, const float* __restrict__ xh, const float* __restrict__ xz,
    const float* __restrict__ bc, const float* __restrict__ A_log, const float* __restrict__ Dpar,
    const float* __restrict__ Hinit, const unsigned short* __restrict__ Whi,
    const unsigned short* __restrict__ Wlo, float* __restrict__ hOut)
{
    __shared__ unsigned short sYh[32*520], sYl[32*520];
    int tid = threadIdx.x;
    int c = blockIdx.x, b = blockIdx.y;
    int m0 = b*T_ + c*LCH;
    {
        int d = tid;
        float a_[16]; ld16(A_log + (size_t)d*16, a_);
#pragma unroll
        for(int n=0;n<16;n++) a_[n] = -__expf(a_[n]);
        float st_[16]; ld16(Hinit + (((size_t)b*NC_ + c)*DI + d)*16, st_);
        float Dp = Dpar[d];
#pragma unroll 4
        for(int t=0;t<32;t++){
            int bt = m0 + t;
            float dtv = dt[(size_t)bt*DI + d];
            float xhv = xh[(size_t)bt*DI + d];
            float bv[16]; ld16(bc + (size_t)bt*32, bv);
            float cv[16]; ld16(bc + (size_t)bt*32 + 16, cv);
            float dx = dtv*xhv;
            float y = 0.f;
#pragma unroll
            for(int n=0;n<16;n++){
                st_[n] = __expf(dtv*a_[n])*st_[n] + dx*bv[n];
                y += st_[n]*cv[n];
            }
            float zv = xz[(size_t)bt*DX + DI + d];
            y += Dp*xhv;
            y = y * zv * sigmoidf_(zv);
            unsigned short hh = f2bf(y);
            sYh[t*520 + d] = hh;
            sYl[t*520 + d] = f2bf(y - bf2f(hh));
        }
    }
    __syncthreads();
    int wave = tid >> 6, lane = tid & 63;
    int lr = lane & 15, kq = (lane>>4)*8, quad4 = (lane>>4)*4;
    f32x4 acc[2][2];
#pragma unroll
    for(int i=0;i<2;i++)
#pragma unroll
        for(int j=0;j<2;j++) acc[i][j] = (f32x4){0.f,0.f,0.f,0.f};
#pragma unroll 4
    for(int ks=0;ks<16;ks++){
        bf16x8 ah[2], al[2];
#pragma unroll
        for(int mi=0;mi<2;mi++){
            int ao = (mi*16 + lr)*520 + ks*32 + kq;
            ah[mi] = *(const bf16x8*)(&sYh[ao]);
            al[mi] = *(const bf16x8*)(&sYl[ao]);
        }
#pragma unroll
        for(int nj=0;nj<2;nj++){
            int n = (wave*2 + nj)*16 + lr;
            size_t wo = (size_t)n*DI + ks*32 + kq;
            bf16x8 bh = *(const bf16x8*)(Whi + wo);
            bf16x8 bl = *(const bf16x8*)(Wlo + wo);
#pragma unroll
            for(int mi=0;mi<2;mi++){
                acc[mi][nj] = __builtin_amdgcn_mfma_f32_16x16x32_bf16(ah[mi], bh, acc[mi][nj], 0,0,0);
                acc[mi][nj] = __builtin_amdgcn_mfma_f32_16x16x32_bf16(ah[mi], bl, acc[mi][nj], 0,0,0);
                acc[mi][nj] = __builtin_amdgcn_mfma_f32_16x16x32_bf16(al[mi], bh, acc[mi][nj], 0,0,0);
            }
        }
    }
#pragma unroll
    for(int mi=0;mi<2;mi++)
#pragma unroll
        for(int nj=0;nj<2;nj++){
            int col = (wave*2 + nj)*16 + lr;
#pragma unroll
            for(int r=0;r<4;r++){
                int row = m0 + mi*16 + quad4 + r;
                hOut[(size_t)row*DM + col] = acc[mi][nj][r];
            }
        }
}

// out[bt] = dot(h[bt, :256], out_W)
__global__ void k_outw(const float* __restrict__ h, const float* __restrict__ ow,
                       float* __restrict__ out){
    int wv = threadIdx.x >> 6, lane = threadIdx.x & 63;
    int bt = blockIdx.x*4 + wv;
    float4 v = ((const float4*)(h + (size_t)bt*DM))[lane];
    float4 w = ((const float4*)ow)[lane];
    float s = v.x*w.x + v.y*w.y + v.z*w.z + v.w*w.w;
#pragma unroll
    for(int m=1;m<64;m<<=1) s += __shfl_xor(s,m);
    if(lane==0) out[bt] = s;
}

extern "C" void kernel_launch(void* const* d_in, const int* in_sizes, int n_in,
                              void* d_out, int out_size, void* d_ws, size_t ws_size,
                              hipStream_t stream){
    const float* x_src    = (const float*)d_in[0];
    const float* in_W     = (const float*)d_in[2];
    const float* norm_w   = (const float*)d_in[3];
    const float* norm_b   = (const float*)d_in[4];
    const float* inproj_W = (const float*)d_in[5];
    const float* conv_w   = (const float*)d_in[6];
    const float* conv_b   = (const float*)d_in[7];
    const float* xproj_W  = (const float*)d_in[8];
    const float* dtproj_W = (const float*)d_in[9];
    const float* dtproj_b = (const float*)d_in[10];
    const float* A_log    = (const float*)d_in[11];
    const float* D_param  = (const float*)d_in[12];
    const float* outproj_W= (const float*)d_in[13];
    const float* out_W    = (const float*)d_in[14];

    float* ws  = (float*)d_ws;
    float* h    = ws;                        // BT*DM (aliased as S during scan)
    float* res  = h    + (size_t)BT_*DM;     // BT*DM
    float* xz   = res  + (size_t)BT_*DM;     // BT*DX
    float* xh   = xz   + (size_t)BT_*DX;     // BT*DI
    float* bcb  = xh   + (size_t)BT_*DI;     // BT*32
    float* dtb  = bcb  + (size_t)BT_*32;     // BT*DI
    float* sdtb = dtb  + (size_t)BT_*DI;     // B*NC*DI
    float* Hbuf = sdtb + (size_t)B_*NC_*DI;  // B*NC*DI*16
    unsigned short* us = (unsigned short*)(Hbuf + (size_t)BT_*DM);
    unsigned short* WhiIn  = us;                                  // NL*DX*DM
    unsigned short* WloIn  = WhiIn  + (size_t)NL*DX*DM;
    unsigned short* WhiOut = WloIn  + (size_t)NL*DX*DM;           // NL*DM*DI
    unsigned short* WloOut = WhiOut + (size_t)NL*DM*DI;
    unsigned short* WhiXp  = WloOut + (size_t)NL*DM*DI;           // NL*NO*DI
    unsigned short* WloXp  = WhiXp  + (size_t)NL*NO_*DI;
    unsigned short* hnhi   = WloXp  + (size_t)NL*NO_*DI;          // BT*DM
    unsigned short* hnlo   = hnhi   + (size_t)BT_*DM;
    float* Sbuf = h;   // dead between resln (consumed) and scan3o (rewritten)

    k_cvtW<<<(NL*DX*DM/4 + 255)/256, 256, 0, stream>>>(inproj_W,  WhiIn,  WloIn,  NL*DX*DM/4);
    k_cvtW<<<(NL*DM*DI/4 + 255)/256, 256, 0, stream>>>(outproj_W, WhiOut, WloOut, NL*DM*DI/4);
    k_cvtW<<<(NL*NO_*DI/4 + 255)/256, 256, 0, stream>>>(xproj_W, WhiXp, WloXp, NL*NO_*DI/4);
    k_ingemm<<<BT_*DM/256, 256, 0, stream>>>(x_src, in_W, h);
    for(int i=0;i<NL;i++){
        k_resln<<<BT_/4, 256, 0, stream>>>(h, res, hnhi, hnlo, norm_w + i*DM, norm_b + i*DM, i>0 ? 1 : 0);
        k_gemm_bf3<128,128><<<dim3(DX/128, BT_/128), 256, 0, stream>>>(
            hnhi, hnlo, WhiIn + (size_t)i*DX*DM, WloIn + (size_t)i*DX*DM, xz, BT_, DX, DM);
        k_convxp<<<BT_/32, 256, 0, stream>>>(xz, conv_w + i*DI*4, conv_b + i*DI,
            WhiXp + (size_t)i*NO_*DI, WloXp + (size_t)i*NO_*DI,
            dtproj_W + (size_t)i*DI*DR_, dtproj_b + i*DI, A_log + (size_t)i*DI*DS_,
            xh, bcb, dtb, Sbuf, sdtb);
        k_scan2<<<B_*DI*DS_/256, 256, 0, stream>>>(Sbuf, sdtb, A_log + (size_t)i*DI*DS_, Hbuf);
        k_scan3o<<<dim3(NC_, B_), 512, 0, stream>>>(dtb, xh, xz, bcb, A_log + (size_t)i*DI*DS_,
            D_param + i*DI, Hbuf, WhiOut + (size_t)i*DM*DI, WloOut + (size_t)i*DM*DI, h);
    }
    k_outw<<<BT_/4, 256, 0, stream>>>(h, out_W, (float*)d_out);
}

// Round 6
// 663.728 us; speedup vs baseline: 4.6041x; 1.0234x over previous
//
#include <hip/hip_runtime.h>

#define B_   4
#define T_   2048
#define BT_  8192
#define INL  15
#define DM   256
#define DI   512
#define DX   1024
#define DS_  16
#define DR_  16
#define NO_  48
#define NL   4
#define NC_  128
#define LCH  16

typedef short bf16x8 __attribute__((ext_vector_type(8)));
typedef float f32x4  __attribute__((ext_vector_type(4)));

__device__ __forceinline__ float sigmoidf_(float x){ return 1.f/(1.f+__expf(-x)); }

__device__ __forceinline__ unsigned short f2bf(float x){
    union { float f; unsigned u; } v; v.f = x;
    unsigned r = (v.u + 0x7FFFu + ((v.u >> 16) & 1u)) >> 16;
    return (unsigned short)r;
}
__device__ __forceinline__ float bf2f(unsigned short h){
    union { unsigned u; float f; } v; v.u = ((unsigned)h) << 16;
    return v.f;
}

__device__ __forceinline__ void ld16(const float* __restrict__ p, float* v){
    const float4* q = (const float4*)p;
    float4 x0=q[0],x1=q[1],x2=q[2],x3=q[3];
    v[0]=x0.x; v[1]=x0.y; v[2]=x0.z; v[3]=x0.w;
    v[4]=x1.x; v[5]=x1.y; v[6]=x1.z; v[7]=x1.w;
    v[8]=x2.x; v[9]=x2.y; v[10]=x2.z; v[11]=x2.w;
    v[12]=x3.x; v[13]=x3.y; v[14]=x3.z; v[15]=x3.w;
}
__device__ __forceinline__ void st16(float* __restrict__ p, const float* v){
    float4* q = (float4*)p;
    q[0] = make_float4(v[0],v[1],v[2],v[3]);
    q[1] = make_float4(v[4],v[5],v[6],v[7]);
    q[2] = make_float4(v[8],v[9],v[10],v[11]);
    q[3] = make_float4(v[12],v[13],v[14],v[15]);
}

// convert fp32 array -> bf16 hi/lo split
__global__ void k_cvtW(const float* __restrict__ W, unsigned short* __restrict__ hi,
                       unsigned short* __restrict__ lo, int n4){
    int g = blockIdx.x*256 + threadIdx.x;
    if(g >= n4) return;
    float4 v = ((const float4*)W)[g];
    ushort4 h, l;
    h.x = f2bf(v.x); l.x = f2bf(v.x - bf2f(h.x));
    h.y = f2bf(v.y); l.y = f2bf(v.y - bf2f(h.y));
    h.z = f2bf(v.z); l.z = f2bf(v.z - bf2f(h.z));
    h.w = f2bf(v.w); l.w = f2bf(v.w - bf2f(h.w));
    ((ushort4*)hi)[g] = h;
    ((ushort4*)lo)[g] = l;
}

// h[bt][m] = sum_k x[bt][k] * in_W[m][k]
__global__ void k_ingemm(const float* __restrict__ x, const float* __restrict__ W,
                         float* __restrict__ h){
    int g  = blockIdx.x*256 + threadIdx.x;
    int bt = g >> 8, m = g & 255;
    const float* xr = x + bt*INL;
    const float* wr = W + m*INL;
    float acc = 0.f;
#pragma unroll
    for(int k=0;k<INL;k++) acc += xr[k]*wr[k];
    h[g] = acc;
}

// res = h (+ res_prev); hn = LN(res)*w+b -> bf16 hi/lo
__global__ void k_resln(const float* __restrict__ h, float* __restrict__ res,
                        unsigned short* __restrict__ hnhi, unsigned short* __restrict__ hnlo,
                        const float* __restrict__ w, const float* __restrict__ b, int addRes){
    int wv = threadIdx.x >> 6, lane = threadIdx.x & 63;
    int bt = blockIdx.x*4 + wv;
    float4 v = ((const float4*)(h + (size_t)bt*DM))[lane];
    if(addRes){
        float4 r = ((const float4*)(res + (size_t)bt*DM))[lane];
        v.x+=r.x; v.y+=r.y; v.z+=r.z; v.w+=r.w;
    }
    ((float4*)(res + (size_t)bt*DM))[lane] = v;
    float s  = v.x+v.y+v.z+v.w;
    float ss = v.x*v.x+v.y*v.y+v.z*v.z+v.w*v.w;
#pragma unroll
    for(int m=1;m<64;m<<=1){ s += __shfl_xor(s,m); ss += __shfl_xor(ss,m); }
    float mean = s*(1.f/DM);
    float var  = ss*(1.f/DM) - mean*mean;
    float inv  = rsqrtf(var + 1e-5f);
    float4 wt = ((const float4*)w)[lane];
    float4 bs = ((const float4*)b)[lane];
    float4 o;
    o.x = (v.x-mean)*inv*wt.x + bs.x;
    o.y = (v.y-mean)*inv*wt.y + bs.y;
    o.z = (v.z-mean)*inv*wt.z + bs.z;
    o.w = (v.w-mean)*inv*wt.w + bs.w;
    ushort4 hh, ll;
    hh.x = f2bf(o.x); ll.x = f2bf(o.x - bf2f(hh.x));
    hh.y = f2bf(o.y); ll.y = f2bf(o.y - bf2f(hh.y));
    hh.z = f2bf(o.z); ll.z = f2bf(o.z - bf2f(hh.z));
    hh.w = f2bf(o.w); ll.w = f2bf(o.w - bf2f(hh.w));
    ((ushort4*)(hnhi + (size_t)bt*DM))[lane] = hh;
    ((ushort4*)(hnlo + (size_t)bt*DM))[lane] = ll;
}

// C[M][N] = A[M][K] @ Bw[N][K]^T via bf16 MFMA, hi/lo 3-term split (inproj)
template<int BM,int BN>
__global__ void __launch_bounds__(256) k_gemm_bf3(
    const unsigned short* __restrict__ Ahi, const unsigned short* __restrict__ Alo,
    const unsigned short* __restrict__ Bhi, const unsigned short* __restrict__ Blo,
    float* __restrict__ C, int M, int N, int K)
{
    constexpr int LDP = 40;
    constexpr int WM = BM/2, WN = BN/2;
    constexpr int MI_ = WM/16, NI_ = WN/16;
    __shared__ unsigned short sAh[BM*LDP], sAl[BM*LDP], sBh[BN*LDP], sBl[BN*LDP];
    int tid  = threadIdx.x;
    int wave = tid >> 6, lane = tid & 63;
    int wm0  = (wave >> 1) * WM, wn0 = (wave & 1) * WN;
    int m0   = blockIdx.y * BM, n0 = blockIdx.x * BN;
    int lr   = lane & 15;
    int kq   = (lane >> 4) * 8;
    int quad4 = (lane >> 4) * 4;

    f32x4 acc[MI_][NI_];
#pragma unroll
    for(int i=0;i<MI_;i++)
#pragma unroll
        for(int j=0;j<NI_;j++) acc[i][j] = (f32x4){0.f,0.f,0.f,0.f};

    for(int k0=0;k0<K;k0+=32){
#pragma unroll
        for(int i=tid;i<BM*4;i+=256){
            int r = i>>2, cg = (i&3)*8;
            size_t go = (size_t)(m0+r)*K + k0 + cg;
            *(float4*)(&sAh[r*LDP + cg]) = *(const float4*)(Ahi + go);
            *(float4*)(&sAl[r*LDP + cg]) = *(const float4*)(Alo + go);
        }
#pragma unroll
        for(int i=tid;i<BN*4;i+=256){
            int r = i>>2, cg = (i&3)*8;
            size_t go = (size_t)(n0+r)*K + k0 + cg;
            *(float4*)(&sBh[r*LDP + cg]) = *(const float4*)(Bhi + go);
            *(float4*)(&sBl[r*LDP + cg]) = *(const float4*)(Blo + go);
        }
        __syncthreads();
        bf16x8 ah[MI_], al[MI_], bh[NI_], bl[NI_];
#pragma unroll
        for(int mi=0;mi<MI_;mi++){
            int ro = (wm0 + mi*16 + lr)*LDP + kq;
            ah[mi] = *(const bf16x8*)(&sAh[ro]);
            al[mi] = *(const bf16x8*)(&sAl[ro]);
        }
#pragma unroll
        for(int ni=0;ni<NI_;ni++){
            int ro = (wn0 + ni*16 + lr)*LDP + kq;
            bh[ni] = *(const bf16x8*)(&sBh[ro]);
            bl[ni] = *(const bf16x8*)(&sBl[ro]);
        }
#pragma unroll
        for(int mi=0;mi<MI_;mi++)
#pragma unroll
            for(int ni=0;ni<NI_;ni++){
                acc[mi][ni] = __builtin_amdgcn_mfma_f32_16x16x32_bf16(ah[mi], bh[ni], acc[mi][ni], 0,0,0);
                acc[mi][ni] = __builtin_amdgcn_mfma_f32_16x16x32_bf16(ah[mi], bl[ni], acc[mi][ni], 0,0,0);
                acc[mi][ni] = __builtin_amdgcn_mfma_f32_16x16x32_bf16(al[mi], bh[ni], acc[mi][ni], 0,0,0);
            }
        __syncthreads();
    }
#pragma unroll
    for(int mi=0;mi<MI_;mi++)
#pragma unroll
        for(int ni=0;ni<NI_;ni++){
            int col = n0 + wn0 + ni*16 + lr;
#pragma unroll
            for(int r=0;r<4;r++){
                int row = m0 + wm0 + mi*16 + quad4 + r;
                C[(size_t)row*N + col] = acc[mi][ni][r];
            }
        }
}

// ---- fused: conv+SiLU -> xh | xproj MFMA -> bc | dtproj+softplus -> dt | scan pass-1 ----
// One block per 16-token chunk (512 blocks, 256 threads = 4 waves, ~2 blocks/CU).
__global__ void __launch_bounds__(256) k_convxp(
    const float* __restrict__ xz, const float* __restrict__ cw, const float* __restrict__ cb,
    const unsigned short* __restrict__ Bhi, const unsigned short* __restrict__ Blo,
    const float* __restrict__ dtW, const float* __restrict__ dtbias,
    const float* __restrict__ A_log,
    float* __restrict__ xh, float* __restrict__ bc, float* __restrict__ dtO,
    float* __restrict__ S, float* __restrict__ sdt)
{
    __shared__ __align__(16) char smem[36352];
    unsigned short* sAh = (unsigned short*)smem;     // 16*140 shorts
    unsigned short* sAl = sAh + 16*140;
    unsigned short* sBh = sAl + 16*140;              // 48*140 shorts
    unsigned short* sBl = sBh + 48*140;
    float* dls  = (float*)smem;                      // 16*17 floats (phase 2)
    float* sdtW = dls + 16*17;                       // 512*17 floats

    int tid = threadIdx.x;
    int wave = tid >> 6, lane = tid & 63;
    int lr = lane & 15, kq = (lane>>4)*8, quad4 = (lane>>4)*4;
    int m0 = blockIdx.x * LCH;
    int tp = tid >> 7;           // token half (0: t 0..7, 1: t 8..15)
    int cI = tid & 127;
    bool mask0 = ((m0 & (T_-1)) == 0) && (tp == 0);

    f32x4 acc = {0.f,0.f,0.f,0.f};

    for(int kc=0;kc<4;kc++){
        int d = kc*128 + cI;
        float4 w4 = *(const float4*)(cw + d*4);
        float bias = cb[d];
        float xv[11];
        int rbase = m0 + tp*8 - 3;
#pragma unroll
        for(int j=0;j<11;j++)
            xv[j] = (mask0 && j<3) ? 0.f : xz[(size_t)(rbase+j)*DX + d];
        for(int i=tid;i<768;i+=256){
            int r = i>>4, cc = (i&15)*8;
            size_t go = (size_t)r*DI + kc*128 + cc;
            *(float4*)(&sBh[r*140 + cc]) = *(const float4*)(Bhi + go);
            *(float4*)(&sBl[r*140 + cc]) = *(const float4*)(Blo + go);
        }
#pragma unroll
        for(int tt=0;tt<8;tt++){
            int t = tp*8 + tt;
            float a = bias + w4.x*xv[tt] + w4.y*xv[tt+1] + w4.z*xv[tt+2] + w4.w*xv[tt+3];
            float v = a * sigmoidf_(a);
            xh[(size_t)(m0+t)*DI + d] = v;
            unsigned short hh = f2bf(v);
            sAh[t*140 + cI] = hh;
            sAl[t*140 + cI] = f2bf(v - bf2f(hh));
        }
        __syncthreads();
        if(wave < 3){
#pragma unroll
            for(int ks=0;ks<4;ks++){
                int ao = lr*140 + ks*32 + kq;
                bf16x8 ah = *(const bf16x8*)(&sAh[ao]);
                bf16x8 al = *(const bf16x8*)(&sAl[ao]);
                int bo = (wave*16 + lr)*140 + ks*32 + kq;
                bf16x8 bh = *(const bf16x8*)(&sBh[bo]);
                bf16x8 bl = *(const bf16x8*)(&sBl[bo]);
                acc = __builtin_amdgcn_mfma_f32_16x16x32_bf16(ah, bh, acc, 0,0,0);
                acc = __builtin_amdgcn_mfma_f32_16x16x32_bf16(ah, bl, acc, 0,0,0);
                acc = __builtin_amdgcn_mfma_f32_16x16x32_bf16(al, bh, acc, 0,0,0);
            }
        }
        __syncthreads();
    }
    // epilogue: rank cols -> dls LDS; B cols / C cols -> bc global
    if(wave == 0){
#pragma unroll
        for(int r=0;r<4;r++) dls[(quad4+r)*17 + lr] = acc[r];
    } else if(wave == 1){
#pragma unroll
        for(int r=0;r<4;r++) bc[(size_t)(m0+quad4+r)*32 + lr] = acc[r];
    } else if(wave == 2){
#pragma unroll
        for(int r=0;r<4;r++) bc[(size_t)(m0+quad4+r)*32 + 16 + lr] = acc[r];
    }
    // stage dtW padded (pitch 17 = conflict-free)
    for(int i=tid;i<DI*16;i+=256)
        sdtW[(i>>4)*17 + (i&15)] = dtW[i];
    __syncthreads();

    int b = m0 >> 11, c = (m0 >> 4) & (NC_-1);
#pragma unroll
    for(int j=0;j<2;j++){
        int d = j*256 + tid;
        float wr_[16];
#pragma unroll
        for(int r=0;r<16;r++) wr_[r] = sdtW[d*17 + r];
        float bsv = dtbias[d];
        float dtreg[LCH];
#pragma unroll
        for(int t=0;t<LCH;t++){
            float acc2 = bsv;
#pragma unroll
            for(int r=0;r<16;r++) acc2 += dls[t*17 + r]*wr_[r];
            float sp = fmaxf(acc2,0.f) + log1pf(__expf(-fabsf(acc2)));
            dtreg[t] = sp;
            dtO[(size_t)(m0+t)*DI + d] = sp;
        }
        float a_[16]; ld16(A_log + (size_t)d*16, a_);
#pragma unroll
        for(int n=0;n<16;n++) a_[n] = -__expf(a_[n]);
        float st_[16];
#pragma unroll
        for(int n=0;n<16;n++) st_[n] = 0.f;
        float sd = 0.f;
#pragma unroll 4
        for(int t=0;t<LCH;t++){
            float dtv = dtreg[t];
            float xhv = xh[(size_t)(m0+t)*DI + d];
            float bv[16]; ld16(bc + (size_t)(m0+t)*32, bv);
            float dx = dtv*xhv;
            sd += dtv;
#pragma unroll
            for(int n=0;n<16;n++) st_[n] = __expf(dtv*a_[n])*st_[n] + dx*bv[n];
        }
        st16(S + (((size_t)b*NC_ + c)*DI + d)*16, st_);
        sdt[((size_t)b*NC_ + c)*DI + d] = sd;
    }
}

// ---- pass 2: inter-chunk scan ----
__global__ void k_scan2(const float* __restrict__ S, const float* __restrict__ sdt,
                        const float* __restrict__ A_log, float* __restrict__ Hinit){
    int g = blockIdx.x*256 + threadIdx.x;
    int b = g >> 13;
    int dn = g & 8191;
    int d = dn >> 4;
    float a = -__expf(A_log[dn]);
    float H = 0.f;
    for(int c=0;c<NC_;c++){
        size_t o = ((size_t)(b*NC_ + c))*8192 + dn;
        Hinit[o] = H;
        float sd = sdt[(size_t)(b*NC_ + c)*DI + d];
        H = __expf(sd*a)*H + S[o];
    }
}

// ---- fused: scan pass-3 replay + gate + outproj MFMA -> h ----
// grid (NC, B) = 512 blocks, 512 threads (8 waves). y tile 16x512 bf16 hi/lo in LDS.
__global__ void __launch_bounds__(512) k_scan3o(
    const float* __restrict__ dt, const float* __restrict__ xh, const float* __restrict__ xz,
    const float* __restrict__ bc, const float* __restrict__ A_log, const float* __restrict__ Dpar,
    const float* __restrict__ Hinit, const unsigned short* __restrict__ Whi,
    const unsigned short* __restrict__ Wlo, float* __restrict__ hOut)
{
    __shared__ unsigned short sYh[16*540], sYl[16*540];
    int tid = threadIdx.x;
    int c = blockIdx.x, b = blockIdx.y;
    int m0 = b*T_ + c*LCH;
    {
        int d = tid;
        float a_[16]; ld16(A_log + (size_t)d*16, a_);
#pragma unroll
        for(int n=0;n<16;n++) a_[n] = -__expf(a_[n]);
        float st_[16]; ld16(Hinit + (((size_t)b*NC_ + c)*DI + d)*16, st_);
        float Dp = Dpar[d];
#pragma unroll 4
        for(int t=0;t<LCH;t++){
            int bt = m0 + t;
            float dtv = dt[(size_t)bt*DI + d];
            float xhv = xh[(size_t)bt*DI + d];
            float bv[16]; ld16(bc + (size_t)bt*32, bv);
            float cv[16]; ld16(bc + (size_t)bt*32 + 16, cv);
            float dx = dtv*xhv;
            float y = 0.f;
#pragma unroll
            for(int n=0;n<16;n++){
                st_[n] = __expf(dtv*a_[n])*st_[n] + dx*bv[n];
                y += st_[n]*cv[n];
            }
            float zv = xz[(size_t)bt*DX + DI + d];
            y += Dp*xhv;
            y = y * zv * sigmoidf_(zv);
            unsigned short hh = f2bf(y);
            sYh[t*540 + d] = hh;
            sYl[t*540 + d] = f2bf(y - bf2f(hh));
        }
    }
    __syncthreads();
    int wave = tid >> 6, lane = tid & 63;
    int lr = lane & 15, kq = (lane>>4)*8, quad4 = (lane>>4)*4;
    f32x4 acc[2];
    acc[0] = (f32x4){0.f,0.f,0.f,0.f};
    acc[1] = (f32x4){0.f,0.f,0.f,0.f};
#pragma unroll 4
    for(int ks=0;ks<16;ks++){
        int ao = lr*540 + ks*32 + kq;
        bf16x8 ah = *(const bf16x8*)(&sYh[ao]);
        bf16x8 al = *(const bf16x8*)(&sYl[ao]);
#pragma unroll
        for(int nj=0;nj<2;nj++){
            int n = (wave*2 + nj)*16 + lr;
            size_t wo = (size_t)n*DI + ks*32 + kq;
            bf16x8 bh = *(const bf16x8*)(Whi + wo);
            bf16x8 bl = *(const bf16x8*)(Wlo + wo);
            acc[nj] = __builtin_amdgcn_mfma_f32_16x16x32_bf16(ah, bh, acc[nj], 0,0,0);
            acc[nj] = __builtin_amdgcn_mfma_f32_16x16x32_bf16(ah, bl, acc[nj], 0,0,0);
            acc[nj] = __builtin_amdgcn_mfma_f32_16x16x32_bf16(al, bh, acc[nj], 0,0,0);
        }
    }
#pragma unroll
    for(int nj=0;nj<2;nj++){
        int col = (wave*2 + nj)*16 + lr;
#pragma unroll
        for(int r=0;r<4;r++){
            int row = m0 + quad4 + r;
            hOut[(size_t)row*DM + col] = acc[nj][r];
        }
    }
}

// out[bt] = dot(h[bt, :256], out_W)
__global__ void k_outw(const float* __restrict__ h, const float* __restrict__ ow,
                       float* __restrict__ out){
    int wv = threadIdx.x >> 6, lane = threadIdx.x & 63;
    int bt = blockIdx.x*4 + wv;
    float4 v = ((const float4*)(h + (size_t)bt*DM))[lane];
    float4 w = ((const float4*)ow)[lane];
    float s = v.x*w.x + v.y*w.y + v.z*w.z + v.w*w.w;
#pragma unroll
    for(int m=1;m<64;m<<=1) s += __shfl_xor(s,m);
    if(lane==0) out[bt] = s;
}

extern "C" void kernel_launch(void* const* d_in, const int* in_sizes, int n_in,
                              void* d_out, int out_size, void* d_ws, size_t ws_size,
                              hipStream_t stream){
    const float* x_src    = (const float*)d_in[0];
    const float* in_W     = (const float*)d_in[2];
    const float* norm_w   = (const float*)d_in[3];
    const float* norm_b   = (const float*)d_in[4];
    const float* inproj_W = (const float*)d_in[5];
    const float* conv_w   = (const float*)d_in[6];
    const float* conv_b   = (const float*)d_in[7];
    const float* xproj_W  = (const float*)d_in[8];
    const float* dtproj_W = (const float*)d_in[9];
    const float* dtproj_b = (const float*)d_in[10];
    const float* A_log    = (const float*)d_in[11];
    const float* D_param  = (const float*)d_in[12];
    const float* outproj_W= (const float*)d_in[13];
    const float* out_W    = (const float*)d_in[14];

    float* ws  = (float*)d_ws;
    float* h    = ws;                        // BT*DM
    float* res  = h    + (size_t)BT_*DM;     // BT*DM
    float* xz   = res  + (size_t)BT_*DM;     // BT*DX
    float* xh   = xz   + (size_t)BT_*DX;     // BT*DI
    float* bcb  = xh   + (size_t)BT_*DI;     // BT*32
    float* dtb  = bcb  + (size_t)BT_*32;     // BT*DI
    float* sdtb = dtb  + (size_t)BT_*DI;     // B*NC*DI
    float* Sbuf = sdtb + (size_t)B_*NC_*DI;  // B*NC*DI*16
    float* Hbuf = Sbuf + (size_t)B_*NC_*DI*DS_;
    unsigned short* us = (unsigned short*)(Hbuf + (size_t)B_*NC_*DI*DS_);
    unsigned short* WhiIn  = us;                                  // NL*DX*DM
    unsigned short* WloIn  = WhiIn  + (size_t)NL*DX*DM;
    unsigned short* WhiOut = WloIn  + (size_t)NL*DX*DM;           // NL*DM*DI
    unsigned short* WloOut = WhiOut + (size_t)NL*DM*DI;
    unsigned short* WhiXp  = WloOut + (size_t)NL*DM*DI;           // NL*NO*DI
    unsigned short* WloXp  = WhiXp  + (size_t)NL*NO_*DI;
    unsigned short* hnhi   = WloXp  + (size_t)NL*NO_*DI;          // BT*DM
    unsigned short* hnlo   = hnhi   + (size_t)BT_*DM;

    k_cvtW<<<(NL*DX*DM/4 + 255)/256, 256, 0, stream>>>(inproj_W,  WhiIn,  WloIn,  NL*DX*DM/4);
    k_cvtW<<<(NL*DM*DI/4 + 255)/256, 256, 0, stream>>>(outproj_W, WhiOut, WloOut, NL*DM*DI/4);
    k_cvtW<<<(NL*NO_*DI/4 + 255)/256, 256, 0, stream>>>(xproj_W, WhiXp, WloXp, NL*NO_*DI/4);
    k_ingemm<<<BT_*DM/256, 256, 0, stream>>>(x_src, in_W, h);
    for(int i=0;i<NL;i++){
        k_resln<<<BT_/4, 256, 0, stream>>>(h, res, hnhi, hnlo, norm_w + i*DM, norm_b + i*DM, i>0 ? 1 : 0);
        k_gemm_bf3<128,128><<<dim3(DX/128, BT_/128), 256, 0, stream>>>(
            hnhi, hnlo, WhiIn + (size_t)i*DX*DM, WloIn + (size_t)i*DX*DM, xz, BT_, DX, DM);
        k_convxp<<<BT_/LCH, 256, 0, stream>>>(xz, conv_w + i*DI*4, conv_b + i*DI,
            WhiXp + (size_t)i*NO_*DI, WloXp + (size_t)i*NO_*DI,
            dtproj_W + (size_t)i*DI*DR_, dtproj_b + i*DI, A_log + (size_t)i*DI*DS_,
            xh, bcb, dtb, Sbuf, sdtb);
        k_scan2<<<B_*DI*DS_/256, 256, 0, stream>>>(Sbuf, sdtb, A_log + (size_t)i*DI*DS_, Hbuf);
        k_scan3o<<<dim3(NC_, B_), 512, 0, stream>>>(dtb, xh, xz, bcb, A_log + (size_t)i*DI*DS_,
            D_param + i*DI, Hbuf, WhiOut + (size_t)i*DM*DI, WloOut + (size_t)i*DM*DI, h);
    }
    k_outw<<<BT_/4, 256, 0, stream>>>(h, out_W, (float*)d_out);
}

// Round 7
// 627.835 us; speedup vs baseline: 4.8673x; 1.0572x over previous
//
#include <hip/hip_runtime.h>

#define B_   4
#define T_   2048
#define BT_  8192
#define INL  15
#define DM   256
#define DI   512
#define DX   1024
#define DS_  16
#define DR_  16
#define NO_  48
#define NL   4
#define NC_  128
#define LCH  16

typedef short bf16x8 __attribute__((ext_vector_type(8)));
typedef float f32x4  __attribute__((ext_vector_type(4)));

__device__ __forceinline__ float sigmoidf_(float x){ return 1.f/(1.f+__expf(-x)); }

__device__ __forceinline__ unsigned short f2bf(float x){
    union { float f; unsigned u; } v; v.f = x;
    unsigned r = (v.u + 0x7FFFu + ((v.u >> 16) & 1u)) >> 16;
    return (unsigned short)r;
}
__device__ __forceinline__ float bf2f(unsigned short h){
    union { unsigned u; float f; } v; v.u = ((unsigned)h) << 16;
    return v.f;
}

__device__ __forceinline__ void ld16(const float* __restrict__ p, float* v){
    const float4* q = (const float4*)p;
    float4 x0=q[0],x1=q[1],x2=q[2],x3=q[3];
    v[0]=x0.x; v[1]=x0.y; v[2]=x0.z; v[3]=x0.w;
    v[4]=x1.x; v[5]=x1.y; v[6]=x1.z; v[7]=x1.w;
    v[8]=x2.x; v[9]=x2.y; v[10]=x2.z; v[11]=x2.w;
    v[12]=x3.x; v[13]=x3.y; v[14]=x3.z; v[15]=x3.w;
}
__device__ __forceinline__ void st16(float* __restrict__ p, const float* v){
    float4* q = (float4*)p;
    q[0] = make_float4(v[0],v[1],v[2],v[3]);
    q[1] = make_float4(v[4],v[5],v[6],v[7]);
    q[2] = make_float4(v[8],v[9],v[10],v[11]);
    q[3] = make_float4(v[12],v[13],v[14],v[15]);
}

// convert fp32 array -> bf16 hi/lo split
__global__ void k_cvtW(const float* __restrict__ W, unsigned short* __restrict__ hi,
                       unsigned short* __restrict__ lo, int n4){
    int g = blockIdx.x*256 + threadIdx.x;
    if(g >= n4) return;
    float4 v = ((const float4*)W)[g];
    ushort4 h, l;
    h.x = f2bf(v.x); l.x = f2bf(v.x - bf2f(h.x));
    h.y = f2bf(v.y); l.y = f2bf(v.y - bf2f(h.y));
    h.z = f2bf(v.z); l.z = f2bf(v.z - bf2f(h.z));
    h.w = f2bf(v.w); l.w = f2bf(v.w - bf2f(h.w));
    ((ushort4*)hi)[g] = h;
    ((ushort4*)lo)[g] = l;
}

// h[bt][m] = sum_k x[bt][k] * in_W[m][k]
__global__ void k_ingemm(const float* __restrict__ x, const float* __restrict__ W,
                         float* __restrict__ h){
    int g  = blockIdx.x*256 + threadIdx.x;
    int bt = g >> 8, m = g & 255;
    const float* xr = x + bt*INL;
    const float* wr = W + m*INL;
    float acc = 0.f;
#pragma unroll
    for(int k=0;k<INL;k++) acc += xr[k]*wr[k];
    h[g] = acc;
}

// res = h (+ res_prev); hn = LN(res)*w+b -> bf16 hi/lo
__global__ void k_resln(const float* __restrict__ h, float* __restrict__ res,
                        unsigned short* __restrict__ hnhi, unsigned short* __restrict__ hnlo,
                        const float* __restrict__ w, const float* __restrict__ b, int addRes){
    int wv = threadIdx.x >> 6, lane = threadIdx.x & 63;
    int bt = blockIdx.x*4 + wv;
    float4 v = ((const float4*)(h + (size_t)bt*DM))[lane];
    if(addRes){
        float4 r = ((const float4*)(res + (size_t)bt*DM))[lane];
        v.x+=r.x; v.y+=r.y; v.z+=r.z; v.w+=r.w;
    }
    ((float4*)(res + (size_t)bt*DM))[lane] = v;
    float s  = v.x+v.y+v.z+v.w;
    float ss = v.x*v.x+v.y*v.y+v.z*v.z+v.w*v.w;
#pragma unroll
    for(int m=1;m<64;m<<=1){ s += __shfl_xor(s,m); ss += __shfl_xor(ss,m); }
    float mean = s*(1.f/DM);
    float var  = ss*(1.f/DM) - mean*mean;
    float inv  = rsqrtf(var + 1e-5f);
    float4 wt = ((const float4*)w)[lane];
    float4 bs = ((const float4*)b)[lane];
    float4 o;
    o.x = (v.x-mean)*inv*wt.x + bs.x;
    o.y = (v.y-mean)*inv*wt.y + bs.y;
    o.z = (v.z-mean)*inv*wt.z + bs.z;
    o.w = (v.w-mean)*inv*wt.w + bs.w;
    ushort4 hh, ll;
    hh.x = f2bf(o.x); ll.x = f2bf(o.x - bf2f(hh.x));
    hh.y = f2bf(o.y); ll.y = f2bf(o.y - bf2f(hh.y));
    hh.z = f2bf(o.z); ll.z = f2bf(o.z - bf2f(hh.z));
    hh.w = f2bf(o.w); ll.w = f2bf(o.w - bf2f(hh.w));
    ((ushort4*)(hnhi + (size_t)bt*DM))[lane] = hh;
    ((ushort4*)(hnlo + (size_t)bt*DM))[lane] = ll;
}

// C[M][N] = A[M][K] @ Bw[N][K]^T via bf16 MFMA, hi/lo 3-term split (inproj)
template<int BM,int BN>
__global__ void __launch_bounds__(256) k_gemm_bf3(
    const unsigned short* __restrict__ Ahi, const unsigned short* __restrict__ Alo,
    const unsigned short* __restrict__ Bhi, const unsigned short* __restrict__ Blo,
    float* __restrict__ C, int M, int N, int K)
{
    constexpr int LDP = 40;
    constexpr int WM = BM/2, WN = BN/2;
    constexpr int MI_ = WM/16, NI_ = WN/16;
    __shared__ unsigned short sAh[BM*LDP], sAl[BM*LDP], sBh[BN*LDP], sBl[BN*LDP];
    int tid  = threadIdx.x;
    int wave = tid >> 6, lane = tid & 63;
    int wm0  = (wave >> 1) * WM, wn0 = (wave & 1) * WN;
    int m0   = blockIdx.y * BM, n0 = blockIdx.x * BN;
    int lr   = lane & 15;
    int kq   = (lane >> 4) * 8;
    int quad4 = (lane >> 4) * 4;

    f32x4 acc[MI_][NI_];
#pragma unroll
    for(int i=0;i<MI_;i++)
#pragma unroll
        for(int j=0;j<NI_;j++) acc[i][j] = (f32x4){0.f,0.f,0.f,0.f};

    for(int k0=0;k0<K;k0+=32){
#pragma unroll
        for(int i=tid;i<BM*4;i+=256){
            int r = i>>2, cg = (i&3)*8;
            size_t go = (size_t)(m0+r)*K + k0 + cg;
            *(float4*)(&sAh[r*LDP + cg]) = *(const float4*)(Ahi + go);
            *(float4*)(&sAl[r*LDP + cg]) = *(const float4*)(Alo + go);
        }
#pragma unroll
        for(int i=tid;i<BN*4;i+=256){
            int r = i>>2, cg = (i&3)*8;
            size_t go = (size_t)(n0+r)*K + k0 + cg;
            *(float4*)(&sBh[r*LDP + cg]) = *(const float4*)(Bhi + go);
            *(float4*)(&sBl[r*LDP + cg]) = *(const float4*)(Blo + go);
        }
        __syncthreads();
        bf16x8 ah[MI_], al[MI_], bh[NI_], bl[NI_];
#pragma unroll
        for(int mi=0;mi<MI_;mi++){
            int ro = (wm0 + mi*16 + lr)*LDP + kq;
            ah[mi] = *(const bf16x8*)(&sAh[ro]);
            al[mi] = *(const bf16x8*)(&sAl[ro]);
        }
#pragma unroll
        for(int ni=0;ni<NI_;ni++){
            int ro = (wn0 + ni*16 + lr)*LDP + kq;
            bh[ni] = *(const bf16x8*)(&sBh[ro]);
            bl[ni] = *(const bf16x8*)(&sBl[ro]);
        }
#pragma unroll
        for(int mi=0;mi<MI_;mi++)
#pragma unroll
            for(int ni=0;ni<NI_;ni++){
                acc[mi][ni] = __builtin_amdgcn_mfma_f32_16x16x32_bf16(ah[mi], bh[ni], acc[mi][ni], 0,0,0);
                acc[mi][ni] = __builtin_amdgcn_mfma_f32_16x16x32_bf16(ah[mi], bl[ni], acc[mi][ni], 0,0,0);
                acc[mi][ni] = __builtin_amdgcn_mfma_f32_16x16x32_bf16(al[mi], bh[ni], acc[mi][ni], 0,0,0);
            }
        __syncthreads();
    }
#pragma unroll
    for(int mi=0;mi<MI_;mi++)
#pragma unroll
        for(int ni=0;ni<NI_;ni++){
            int col = n0 + wn0 + ni*16 + lr;
#pragma unroll
            for(int r=0;r<4;r++){
                int row = m0 + wm0 + mi*16 + quad4 + r;
                C[(size_t)row*N + col] = acc[mi][ni][r];
            }
        }
}

// ---- fused: conv+SiLU | xproj MFMA (B streamed from L2) | dtproj | scan pass-1 ----
// 512 threads, thread = d-channel throughout; xh stays in REGISTERS, bc in LDS.
__global__ void __launch_bounds__(512) k_convxp(
    const float* __restrict__ xz, const float* __restrict__ cw, const float* __restrict__ cb,
    const unsigned short* __restrict__ Bhi, const unsigned short* __restrict__ Blo,
    const float* __restrict__ dtW, const float* __restrict__ dtbias,
    const float* __restrict__ A_log,
    float* __restrict__ xh, float* __restrict__ bc, float* __restrict__ dtO,
    float* __restrict__ S, float* __restrict__ sdt)
{
    __shared__ unsigned short sAh[16*520], sAl[16*520];
    __shared__ float sbc[16*36];
    __shared__ float dls[16*17];

    int tid = threadIdx.x;
    int wave = tid >> 6, lane = tid & 63;
    int lr = lane & 15, kq = (lane>>4)*8, quad4 = (lane>>4)*4;
    int m0 = blockIdx.x * LCH;
    int d  = tid;

    // ---- phase A: conv + SiLU; xh kept in registers ----
    float xv[19];
    {
        int rbase = m0 - 3;
        bool mask0 = ((m0 & (T_-1)) == 0);
#pragma unroll
        for(int j=0;j<19;j++)
            xv[j] = (mask0 && j<3) ? 0.f : xz[(size_t)(rbase+j)*DX + d];
    }
    float4 w4 = *(const float4*)(cw + d*4);
    float bias = cb[d];
    float xhreg[16];
#pragma unroll
    for(int t=0;t<16;t++){
        float a = bias + w4.x*xv[t] + w4.y*xv[t+1] + w4.z*xv[t+2] + w4.w*xv[t+3];
        float v = a * sigmoidf_(a);
        xhreg[t] = v;
        xh[(size_t)(m0+t)*DI + d] = v;
        unsigned short hh = f2bf(v);
        sAh[t*520 + d] = hh;
        sAl[t*520 + d] = f2bf(v - bf2f(hh));
    }
    // per-thread params (coalesced 64B/lane blocks, overlap with MFMA phase)
    float wr_[16]; ld16(dtW + (size_t)d*16, wr_);
    float a_[16];  ld16(A_log + (size_t)d*16, a_);
#pragma unroll
    for(int n=0;n<16;n++) a_[n] = -__expf(a_[n]);
    float bsv = dtbias[d];
    __syncthreads();

    // ---- phase B: xproj MFMA, waves 0-2 = n-tiles, B streamed from global (L2-hot) ----
    f32x4 acc = {0.f,0.f,0.f,0.f};
    if(wave < 3){
#pragma unroll 4
        for(int ks=0;ks<16;ks++){
            int ao = lr*520 + ks*32 + kq;
            bf16x8 ah = *(const bf16x8*)(&sAh[ao]);
            bf16x8 al = *(const bf16x8*)(&sAl[ao]);
            size_t wo = (size_t)(wave*16 + lr)*DI + ks*32 + kq;
            bf16x8 bh = *(const bf16x8*)(Bhi + wo);
            bf16x8 bl = *(const bf16x8*)(Blo + wo);
            acc = __builtin_amdgcn_mfma_f32_16x16x32_bf16(ah, bh, acc, 0,0,0);
            acc = __builtin_amdgcn_mfma_f32_16x16x32_bf16(ah, bl, acc, 0,0,0);
            acc = __builtin_amdgcn_mfma_f32_16x16x32_bf16(al, bh, acc, 0,0,0);
        }
        // epilogue: dt-rank cols -> dls; B cols -> sbc[0..15]+global; C cols -> sbc[16..31]+global
        if(wave == 0){
#pragma unroll
            for(int r=0;r<4;r++) dls[(quad4+r)*17 + lr] = acc[r];
        } else if(wave == 1){
#pragma unroll
            for(int r=0;r<4;r++){
                sbc[(quad4+r)*36 + lr] = acc[r];
                bc[(size_t)(m0+quad4+r)*32 + lr] = acc[r];
            }
        } else {
#pragma unroll
            for(int r=0;r<4;r++){
                sbc[(quad4+r)*36 + 16 + lr] = acc[r];
                bc[(size_t)(m0+quad4+r)*32 + 16 + lr] = acc[r];
            }
        }
    }
    __syncthreads();

    // ---- phase D: dtproj + softplus + scan pass-1, one d per thread, zero global re-reads ----
    float dtreg[16];
#pragma unroll
    for(int t=0;t<16;t++){
        float acc2 = bsv;
#pragma unroll
        for(int r=0;r<16;r++) acc2 += dls[t*17 + r]*wr_[r];
        float sp = fmaxf(acc2,0.f) + log1pf(__expf(-fabsf(acc2)));
        dtreg[t] = sp;
        dtO[(size_t)(m0+t)*DI + d] = sp;
    }
    float st_[16];
#pragma unroll
    for(int n=0;n<16;n++) st_[n] = 0.f;
    float sd = 0.f;
#pragma unroll 4
    for(int t=0;t<16;t++){
        float dtv = dtreg[t];
        float dx  = dtv*xhreg[t];
        sd += dtv;
        float bv[16]; ld16(&sbc[t*36], bv);
#pragma unroll
        for(int n=0;n<16;n++) st_[n] = __expf(dtv*a_[n])*st_[n] + dx*bv[n];
    }
    int b = m0 >> 11, c = (m0 >> 4) & (NC_-1);
    st16(S + (((size_t)b*NC_ + c)*DI + d)*16, st_);
    sdt[((size_t)b*NC_ + c)*DI + d] = sd;
}

// ---- pass 2: inter-chunk scan ----
__global__ void k_scan2(const float* __restrict__ S, const float* __restrict__ sdt,
                        const float* __restrict__ A_log, float* __restrict__ Hinit){
    int g = blockIdx.x*256 + threadIdx.x;
    int b = g >> 13;
    int dn = g & 8191;
    int d = dn >> 4;
    float a = -__expf(A_log[dn]);
    float H = 0.f;
    for(int c=0;c<NC_;c++){
        size_t o = ((size_t)(b*NC_ + c))*8192 + dn;
        Hinit[o] = H;
        float sd = sdt[(size_t)(b*NC_ + c)*DI + d];
        H = __expf(sd*a)*H + S[o];
    }
}

// ---- fused: scan pass-3 replay + gate + outproj MFMA -> h. bc staged in LDS. ----
__global__ void __launch_bounds__(512) k_scan3o(
    const float* __restrict__ dt, const float* __restrict__ xh, const float* __restrict__ xz,
    const float* __restrict__ bc, const float* __restrict__ A_log, const float* __restrict__ Dpar,
    const float* __restrict__ Hinit, const unsigned short* __restrict__ Whi,
    const unsigned short* __restrict__ Wlo, float* __restrict__ hOut)
{
    __shared__ unsigned short sYh[16*540], sYl[16*540];
    __shared__ float sbc[16*36];
    int tid = threadIdx.x;
    int c = blockIdx.x, b = blockIdx.y;
    int m0 = b*T_ + c*LCH;
    if(tid < 128){
        int t = tid >> 3, s = tid & 7;
        *(float4*)(&sbc[t*36 + s*4]) = *(const float4*)(bc + (size_t)(m0+t)*32 + s*4);
    }
    __syncthreads();
    {
        int d = tid;
        float a_[16]; ld16(A_log + (size_t)d*16, a_);
#pragma unroll
        for(int n=0;n<16;n++) a_[n] = -__expf(a_[n]);
        float st_[16]; ld16(Hinit + (((size_t)b*NC_ + c)*DI + d)*16, st_);
        float Dp = Dpar[d];
#pragma unroll 4
        for(int t=0;t<LCH;t++){
            int bt = m0 + t;
            float dtv = dt[(size_t)bt*DI + d];
            float xhv = xh[(size_t)bt*DI + d];
            float bv[16]; ld16(&sbc[t*36], bv);
            float cv[16]; ld16(&sbc[t*36 + 16], cv);
            float dx = dtv*xhv;
            float y = 0.f;
#pragma unroll
            for(int n=0;n<16;n++){
                st_[n] = __expf(dtv*a_[n])*st_[n] + dx*bv[n];
                y += st_[n]*cv[n];
            }
            float zv = xz[(size_t)bt*DX + DI + d];
            y += Dp*xhv;
            y = y * zv * sigmoidf_(zv);
            unsigned short hh = f2bf(y);
            sYh[t*540 + d] = hh;
            sYl[t*540 + d] = f2bf(y - bf2f(hh));
        }
    }
    __syncthreads();
    int wave = tid >> 6, lane = tid & 63;
    int lr = lane & 15, kq = (lane>>4)*8, quad4 = (lane>>4)*4;
    f32x4 acc[2];
    acc[0] = (f32x4){0.f,0.f,0.f,0.f};
    acc[1] = (f32x4){0.f,0.f,0.f,0.f};
#pragma unroll 4
    for(int ks=0;ks<16;ks++){
        int ao = lr*540 + ks*32 + kq;
        bf16x8 ah = *(const bf16x8*)(&sYh[ao]);
        bf16x8 al = *(const bf16x8*)(&sYl[ao]);
#pragma unroll
        for(int nj=0;nj<2;nj++){
            int n = (wave*2 + nj)*16 + lr;
            size_t wo = (size_t)n*DI + ks*32 + kq;
            bf16x8 bh = *(const bf16x8*)(Whi + wo);
            bf16x8 bl = *(const bf16x8*)(Wlo + wo);
            acc[nj] = __builtin_amdgcn_mfma_f32_16x16x32_bf16(ah, bh, acc[nj], 0,0,0);
            acc[nj] = __builtin_amdgcn_mfma_f32_16x16x32_bf16(ah, bl, acc[nj], 0,0,0);
            acc[nj] = __builtin_amdgcn_mfma_f32_16x16x32_bf16(al, bh, acc[nj], 0,0,0);
        }
    }
#pragma unroll
    for(int nj=0;nj<2;nj++){
        int col = (wave*2 + nj)*16 + lr;
#pragma unroll
        for(int r=0;r<4;r++){
            int row = m0 + quad4 + r;
            hOut[(size_t)row*DM + col] = acc[nj][r];
        }
    }
}

// out[bt] = dot(h[bt, :256], out_W)
__global__ void k_outw(const float* __restrict__ h, const float* __restrict__ ow,
                       float* __restrict__ out){
    int wv = threadIdx.x >> 6, lane = threadIdx.x & 63;
    int bt = blockIdx.x*4 + wv;
    float4 v = ((const float4*)(h + (size_t)bt*DM))[lane];
    float4 w = ((const float4*)ow)[lane];
    float s = v.x*w.x + v.y*w.y + v.z*w.z + v.w*w.w;
#pragma unroll
    for(int m=1;m<64;m<<=1) s += __shfl_xor(s,m);
    if(lane==0) out[bt] = s;
}

extern "C" void kernel_launch(void* const* d_in, const int* in_sizes, int n_in,
                              void* d_out, int out_size, void* d_ws, size_t ws_size,
                              hipStream_t stream){
    const float* x_src    = (const float*)d_in[0];
    const float* in_W     = (const float*)d_in[2];
    const float* norm_w   = (const float*)d_in[3];
    const float* norm_b   = (const float*)d_in[4];
    const float* inproj_W = (const float*)d_in[5];
    const float* conv_w   = (const float*)d_in[6];
    const float* conv_b   = (const float*)d_in[7];
    const float* xproj_W  = (const float*)d_in[8];
    const float* dtproj_W = (const float*)d_in[9];
    const float* dtproj_b = (const float*)d_in[10];
    const float* A_log    = (const float*)d_in[11];
    const float* D_param  = (const float*)d_in[12];
    const float* outproj_W= (const float*)d_in[13];
    const float* out_W    = (const float*)d_in[14];

    float* ws  = (float*)d_ws;
    float* h    = ws;                        // BT*DM
    float* res  = h    + (size_t)BT_*DM;     // BT*DM
    float* xz   = res  + (size_t)BT_*DM;     // BT*DX
    float* xh   = xz   + (size_t)BT_*DX;     // BT*DI
    float* bcb  = xh   + (size_t)BT_*DI;     // BT*32
    float* dtb  = bcb  + (size_t)BT_*32;     // BT*DI
    float* sdtb = dtb  + (size_t)BT_*DI;     // B*NC*DI
    float* Sbuf = sdtb + (size_t)B_*NC_*DI;  // B*NC*DI*16
    float* Hbuf = Sbuf + (size_t)B_*NC_*DI*DS_;
    unsigned short* us = (unsigned short*)(Hbuf + (size_t)B_*NC_*DI*DS_);
    unsigned short* WhiIn  = us;                                  // NL*DX*DM
    unsigned short* WloIn  = WhiIn  + (size_t)NL*DX*DM;
    unsigned short* WhiOut = WloIn  + (size_t)NL*DX*DM;           // NL*DM*DI
    unsigned short* WloOut = WhiOut + (size_t)NL*DM*DI;
    unsigned short* WhiXp  = WloOut + (size_t)NL*DM*DI;           // NL*NO*DI
    unsigned short* WloXp  = WhiXp  + (size_t)NL*NO_*DI;
    unsigned short* hnhi   = WloXp  + (size_t)NL*NO_*DI;          // BT*DM
    unsigned short* hnlo   = hnhi   + (size_t)BT_*DM;

    k_cvtW<<<(NL*DX*DM/4 + 255)/256, 256, 0, stream>>>(inproj_W,  WhiIn,  WloIn,  NL*DX*DM/4);
    k_cvtW<<<(NL*DM*DI/4 + 255)/256, 256, 0, stream>>>(outproj_W, WhiOut, WloOut, NL*DM*DI/4);
    k_cvtW<<<(NL*NO_*DI/4 + 255)/256, 256, 0, stream>>>(xproj_W, WhiXp, WloXp, NL*NO_*DI/4);
    k_ingemm<<<BT_*DM/256, 256, 0, stream>>>(x_src, in_W, h);
    for(int i=0;i<NL;i++){
        k_resln<<<BT_/4, 256, 0, stream>>>(h, res, hnhi, hnlo, norm_w + i*DM, norm_b + i*DM, i>0 ? 1 : 0);
        k_gemm_bf3<128,128><<<dim3(DX/128, BT_/128), 256, 0, stream>>>(
            hnhi, hnlo, WhiIn + (size_t)i*DX*DM, WloIn + (size_t)i*DX*DM, xz, BT_, DX, DM);
        k_convxp<<<BT_/LCH, 512, 0, stream>>>(xz, conv_w + i*DI*4, conv_b + i*DI,
            WhiXp + (size_t)i*NO_*DI, WloXp + (size_t)i*NO_*DI,
            dtproj_W + (size_t)i*DI*DR_, dtproj_b + i*DI, A_log + (size_t)i*DI*DS_,
            xh, bcb, dtb, Sbuf, sdtb);
        k_scan2<<<B_*DI*DS_/256, 256, 0, stream>>>(Sbuf, sdtb, A_log + (size_t)i*DI*DS_, Hbuf);
        k_scan3o<<<dim3(NC_, B_), 512, 0, stream>>>(dtb, xh, xz, bcb, A_log + (size_t)i*DI*DS_,
            D_param + i*DI, Hbuf, WhiOut + (size_t)i*DM*DI, WloOut + (size_t)i*DM*DI, h);
    }
    k_outw<<<BT_/4, 256, 0, stream>>>(h, out_W, (float*)d_out);
}